// Round 16
// baseline (10717.104 us; speedup 1.0000x reference)
//
#include <hip/hip_runtime.h>
#include <stdint.h>

// PolicyNetRSNNPB R16 = R15 with PHYSICAL XCD claiming restored (one-variable
// fix). R15 showed 128 VGPR + x=blockIdx&7 still fetches 14GB: the blockIdx
// round-robin assumption does NOT match physical XCD placement -> gathers hit
// remote slices -> HBM. R4-R12 used s_getreg(HW_REG_XCC_ID) + atomic rank
// claim and always kept FETCH <3GB. R16: physical claim with rank&63 (64
// groups x 8 blocks; co-residency at 2 blk/CU guarantees exactly 64/XCD).
// Grid-256/SPW=2 fallback (R11 geometry, rank&31). Everything else = R15.
// Bit-exact order preserved (absmax 0.0 through R15).

typedef unsigned long long u64;
typedef unsigned int u32;
typedef float f32x4 __attribute__((ext_vector_type(4)));

#define NB 512
#define HD 2048
#define ROWS 2049          // 2048 + zero row
#define NSTEPS 128
#define THREADS 512
#define COLS 256
#define NWPS 32
#define LSTN 2080          // 8*2080*2B = 33,280B LDS -> 2 blocks/CU possible
#define ZROW 2048

#define DMc 0.8187307530779818f
#define DSc 0.6065306597126334f
#define SMc 0.18126924692201818f

// ---- ws layout ----
#define OFF_M1W 0
#define SZ_M1W ((size_t)2 * NB * NWPS * 8)       // 256 KB
#define OFF_M2H (OFF_M1W + SZ_M1W)
#define SZ_M2H ((size_t)NSTEPS * NB * NWPS * 8)  // 16 MB
#define OFF_SLOT (OFF_M2H + SZ_M2H)              // u32 per (g,x), 128B stride
#define SZ_SLOT (64 * 8 * 128)
#define OFF_CNT (OFF_SLOT + SZ_SLOT)             // u32[8] xcd rank counters
#define OFF_DONE (OFF_CNT + 64)
#define OFF_PK (((size_t)(OFF_DONE + 64) + 4194303) & ~(size_t)4194303)
#define SZ_PK ((size_t)8 * ROWS * 512 * 4)       // ~33.6 MB
#define OFF_XW (((OFF_PK + SZ_PK) + 255) & ~(size_t)255)
#define SZ_XW ((size_t)64 * NB * HD * 4)         // 256 MB

#define HWREG_XCC_ID (20 | ((4 - 1) << 11))
#define SLOT(base, g, x) ((base) + ((size_t)((g)*8 + (x)) * 32))

__global__ void init_ws(u64* __restrict__ m1W, u32* __restrict__ slots,
                        u32* __restrict__ cnt, u32* __restrict__ done) {
  int i = blockIdx.x * 256 + threadIdx.x;
  if (i < 2 * NB * NWPS) m1W[i] = 0ULL;
  if (i < 64 * 8 * 32) slots[i] = 0u;
  if (i < 8) cnt[i] = 0u;
  if (i == 0) *done = 0u;
}

// PK[x][k][0..255]=Vr[k][x*256+..], [256..511]=Wf[k][..]; row 2048 = zeros
__global__ __launch_bounds__(256) void pack_kernel(
    const float* __restrict__ Vr, const float* __restrict__ Wf,
    float* __restrict__ PK) {
  const int k = blockIdx.x;
  const int tid = threadIdx.x;
  for (int c = tid; c < HD; c += 256) {
    int x = c >> 8, cc = c & 255;
    size_t base = ((size_t)x * ROWS + k) * 512;
    float v = (k < HD) ? Vr[(size_t)k * HD + c] : 0.0f;
    float w = (k < HD) ? Wf[(size_t)k * HD + c] : 0.0f;
    __builtin_nontemporal_store(v, &PK[base + cc]);
    __builtin_nontemporal_store(w, &PK[base + 256 + cc]);
  }
}

// XW[t*NB+n][h] = bi[h] + x(t,n,:) @ Wi
__global__ __launch_bounds__(256) void xw_kernel(
    const float* __restrict__ state, const float* __restrict__ target,
    const float* __restrict__ Wi, const float* __restrict__ bi,
    float* __restrict__ XW) {
  __shared__ float xl[16][128];
  const int tid = threadIdx.x;
  const int col = blockIdx.x * 256 + tid;
  const int r0 = blockIdx.y * 16;

  for (int idx = tid; idx < 16 * 128; idx += 256) {
    int r = idx >> 7, k = idx & 127;
    int gg = r0 + r;
    int t = gg >> 9, n = gg & 511;
    float v = (k < 64) ? state[((size_t)(t * NB + n)) * 64 + k]
                       : target[((size_t)(t * NB + n)) * 64 + (k - 64)];
    xl[r][k] = v;
  }
  __syncthreads();

  float acc[16];
  float b = bi[col];
#pragma unroll
  for (int r = 0; r < 16; ++r) acc[r] = b;
  for (int k = 0; k < 128; ++k) {
    float w = Wi[(size_t)k * HD + col];
#pragma unroll
    for (int r = 0; r < 16; ++r) acc[r] = fmaf(xl[r][k], w, acc[r]);
  }
#pragma unroll
  for (int r = 0; r < 16; ++r)
    __builtin_nontemporal_store(acc[r], &XW[(size_t)(r0 + r) * HD + col]);
}

__device__ __forceinline__ u64 spread4(u64 x) {
  x &= 0xffffULL;
  x = (x | (x << 24)) & 0x000000FF000000FFULL;
  x = (x | (x << 12)) & 0x000F000F000F000FULL;
  x = (x | (x << 6))  & 0x0303030303030303ULL;
  x = (x | (x << 3))  & 0x1111111111111111ULL;
  return x;
}

__device__ __forceinline__ u64 pack_word(u64 B0, u64 B1, u64 B2, u64 B3, int q) {
  int sh = q * 16;
  return spread4(B0 >> sh) | (spread4(B1 >> sh) << 1) |
         (spread4(B2 >> sh) << 2) | (spread4(B3 >> sh) << 3);
}

// one-sample list build from MALL masks; ascending; pad to x8 with ZROW.
__device__ __forceinline__ int build_one(const u64* __restrict__ mw,
                                         uint16_t* __restrict__ lst, int lane) {
  u64 w = 0ULL;
  if (lane < NWPS)
    w = __hip_atomic_load((u64*)&mw[lane], __ATOMIC_RELAXED,
                          __HIP_MEMORY_SCOPE_AGENT);
  int pc = __popcll(w);
  int pre = pc;
#pragma unroll
  for (int off = 1; off < 64; off <<= 1) {
    int v = __shfl_up(pre, off);
    if (lane >= off) pre += v;
  }
  int excl = pre - pc;
  int total = __shfl(pre, 63);
  int kb = lane << 6;
  while (w) {
    int b = __builtin_ctzll(w);
    w &= w - 1;
    lst[excl++] = (uint16_t)(kb + b);
  }
  int r8 = (total + 7) & ~7;
  if (lane < 8 && total + lane < r8) lst[total + lane] = (uint16_t)ZROW;
  asm volatile("s_waitcnt lgkmcnt(0)" ::: "memory");
  return r8;
}

// readout-tail list build (plain loads)
__device__ __forceinline__ int build_list_ro(const u64* __restrict__ mwords,
                                             uint16_t* __restrict__ lstw,
                                             int lane) {
  u64 w = (lane < NWPS) ? mwords[lane] : 0ULL;
  int pc = __popcll(w);
  int pre = pc;
#pragma unroll
  for (int off = 1; off < 64; off <<= 1) {
    int v = __shfl_up(pre, off);
    if (lane >= off) pre += v;
  }
  int excl = pre - pc;
  int total = __shfl(pre, 63);
  int kb = lane << 6;
  while (w) {
    int b = __builtin_ctzll(w);
    w &= w - 1;
    lstw[excl++] = (uint16_t)(kb + b);
  }
  asm volatile("s_waitcnt lgkmcnt(0)" ::: "memory");
  return total;
}

__device__ __forceinline__ u32 lif_update(const float acc[4], float syn[4],
                                          float mem[4], u32 snib) {
  u32 nib = 0;
#pragma unroll
  for (int j = 0; j < 4; ++j) {
    float so = (float)((snib >> j) & 1u);
    float nmem = (DMc * mem[j] + SMc * syn[j]) * (1.0f - so);  // R1 shape
    float nsyn = DSc * syn[j] + acc[j];                         // R1 shape
    mem[j] = nmem;
    syn[j] = nsyn;
    if ((nmem - 1.0f) > 0.0f) nib |= (1u << j);
  }
  return nib;
}

// unguarded dual gather (zero-row padded list): addr + 2 loads + 8 adds per
// element, 16 loads in flight, ascending k; trailing +0.0 adds exact.
__device__ __forceinline__ void gather_one(const float* __restrict__ PKb,
                                           const uint16_t* __restrict__ lst,
                                           int r8, float aV[4], float aW[4]) {
  for (int j0 = 0; j0 < r8; j0 += 8) {
    f32x4 v[8], w8[8];
#pragma unroll
    for (int u = 0; u < 8; ++u) {
      size_t off = ((size_t)lst[j0 + u]) << 9;
      v[u] = *(const f32x4*)(PKb + off);
      w8[u] = *(const f32x4*)(PKb + off + 256);
    }
#pragma unroll
    for (int u = 0; u < 8; ++u) {
      aV[0] += v[u].x; aV[1] += v[u].y; aV[2] += v[u].z; aV[3] += v[u].w;
      aW[0] += w8[u].x; aW[1] += w8[u].y; aW[2] += w8[u].z; aW[3] += w8[u].w;
    }
  }
}

// SPW = samples per wave (1: grid 512, 2 blk/CU, rank&63; 2: grid 256, rank&31)
template <int SPW, int UXW>
__global__ __launch_bounds__(THREADS, 2) void rsnn_coop(
    const float* __restrict__ state, const float* __restrict__ target,
    const float* __restrict__ Wi, const float* __restrict__ bi,
    const float* __restrict__ Vr, const float* __restrict__ Wf,
    const float* __restrict__ bf, const float* __restrict__ Wo,
    const float* __restrict__ bo, float* __restrict__ out,
    char* __restrict__ wsb) {
  __shared__ uint16_t lst_s[8][LSTN];   // 33,280 B
  __shared__ int sh_x, sh_g;

  u64* m1W = (u64*)(wsb + OFF_M1W);
  u64* m2H = (u64*)(wsb + OFF_M2H);
  u32* slots = (u32*)(wsb + OFF_SLOT);
  u32* cnt = (u32*)(wsb + OFF_CNT);
  u32* done = (u32*)(wsb + OFF_DONE);
  const float* PK = (const float*)(wsb + OFF_PK);
  const float* XW = (const float*)(wsb + OFF_XW);

  const int tid = threadIdx.x;
  const int wv = tid >> 6;      // 0..7
  const int lane = tid & 63;    // lane = 4 columns

  // physical XCD claim: slice = real XCD; rank = group id (exact partition:
  // co-residency guarantees 64 (SPW=1) or 32 (SPW=2) blocks per XCD)
  if (tid == 0) {
    int xx = __builtin_amdgcn_s_getreg(HWREG_XCC_ID) & 7;
    sh_x = xx;
    sh_g = atomicAdd(&cnt[xx], 1u) & (SPW == 1 ? 63 : 31);
  }
  __syncthreads();
  const int x = sh_x;
  const int g = sh_g;
  const int c0 = x * COLS;
  const int s0 = (g * 8 + wv) * SPW;     // first sample of this wave

  uint16_t* lst = &lst_s[wv][0];

  float bir[4], bfr[4];
#pragma unroll
  for (int j = 0; j < 4; ++j) {
    bir[j] = bi[c0 + lane * 4 + j];
    bfr[j] = bf[c0 + lane * 4 + j];
  }

  float syn1[SPW][4], mem1[SPW][4], syn2[SPW][4], mem2[SPW][4];
#pragma unroll
  for (int r = 0; r < SPW; ++r)
#pragma unroll
    for (int j = 0; j < 4; ++j) {
      syn1[r][j] = 0.f; mem1[r][j] = 0.f; syn2[r][j] = 0.f; mem2[r][j] = 0.f;
    }
  u32 nib1[SPW], nib2[SPW];
#pragma unroll
  for (int r = 0; r < SPW; ++r) { nib1[r] = 0u; nib2[r] = 0u; }
  float xw[SPW][4];
  f32x4 xwN[SPW];

  const float* PKb = PK + (size_t)x * ROWS * 512 + lane * 4;
  const float* XWc = XW + c0 + lane * 4;

  // fallback xw (k-ascending fmaf from global Wi)
  auto compute_xw = [&](int t2, int r) {
#pragma unroll
    for (int j = 0; j < 4; ++j) xw[r][j] = bir[j];
#pragma unroll
    for (int half = 0; half < 2; ++half) {
      const float* p =
          (half ? target : state) + ((size_t)t2 * NB + s0 + r) * 64;
      for (int q = 0; q < 16; ++q) {
        f32x4 xq = *(const f32x4*)(p + 4 * q);
        float xv[4] = {xq.x, xq.y, xq.z, xq.w};
#pragma unroll
        for (int kj = 0; kj < 4; ++kj) {
          const f32x4 w4 = *(const f32x4*)&Wi[(size_t)(half * 64 + 4 * q + kj) *
                                                  HD + c0 + lane * 4];
          xw[r][0] = fmaf(xv[kj], w4.x, xw[r][0]);
          xw[r][1] = fmaf(xv[kj], w4.y, xw[r][1]);
          xw[r][2] = fmaf(xv[kj], w4.z, xw[r][2]);
          xw[r][3] = fmaf(xv[kj], w4.w, xw[r][3]);
        }
      }
    }
  };

  // ---- prologue: xw(0); LIF1(0); publish m1(0); barrier; arrive 1; poll ----
#pragma unroll
  for (int r = 0; r < SPW; ++r) {
    if constexpr (UXW) {
      f32x4 a = __builtin_nontemporal_load(
          (const f32x4*)(XWc + (size_t)(s0 + r) * HD));
      xw[r][0] = a.x; xw[r][1] = a.y; xw[r][2] = a.z; xw[r][3] = a.w;
    } else {
      compute_xw(0, r);
    }
    nib1[r] = lif_update(xw[r], syn1[r], mem1[r], 0u);
    u64 E0 = __ballot(nib1[r] & 1u), E1 = __ballot(nib1[r] & 2u);
    u64 E2 = __ballot(nib1[r] & 4u), E3 = __ballot(nib1[r] & 8u);
    if (lane < 4)
      __hip_atomic_store(&m1W[(size_t)(s0 + r) * NWPS + 4 * x + lane],
                         pack_word(E0, E1, E2, E3, lane), __ATOMIC_RELAXED,
                         __HIP_MEMORY_SCOPE_AGENT);
  }
  __syncthreads();
  if (tid == 0)
    __hip_atomic_store(SLOT(slots, g, x), 1u, __ATOMIC_RELAXED,
                       __HIP_MEMORY_SCOPE_AGENT);
  __syncthreads();
  if (tid == 0) {
    while (true) {
      u32 mn = 0xffffffffu;
#pragma unroll
      for (int x2 = 0; x2 < 8; ++x2) {
        u32 v = __hip_atomic_load(SLOT(slots, g, x2), __ATOMIC_RELAXED,
                                  __HIP_MEMORY_SCOPE_AGENT);
        mn = v < mn ? v : mn;
      }
      if (mn >= 1u) break;
      __builtin_amdgcn_s_sleep(1);
    }
  }
  __syncthreads();

  // ---- main loop: step s gathers with m1(s); xw holds t=(s+1)>>1 ----
  for (int s = 0; s < NSTEPS; ++s) {
    const bool last = (s == NSTEPS - 1);
    if (s & 1) {
#pragma unroll
      for (int r = 0; r < SPW; ++r) {
        if constexpr (UXW) {
          xw[r][0] = xwN[r].x; xw[r][1] = xwN[r].y;
          xw[r][2] = xwN[r].z; xw[r][3] = xwN[r].w;
        } else {
          if (s + 1 < NSTEPS) compute_xw((s + 1) >> 1, r);
        }
      }
    }

    const u64* m1cur = m1W + (size_t)(s & 1) * NB * NWPS;
    u64* m1n = m1W + (size_t)((s + 1) & 1) * NB * NWPS;

    __builtin_amdgcn_s_setprio(1);
#pragma unroll
    for (int r = 0; r < SPW; ++r) {
      const int smp = s0 + r;
      int r8 = build_one(m1cur + (size_t)smp * NWPS, lst, lane);
      float aV[4] = {xw[r][0], xw[r][1], xw[r][2], xw[r][3]};
      float aW[4] = {bfr[0], bfr[1], bfr[2], bfr[3]};
      gather_one(PKb, lst, r8, aV, aW);

      nib2[r] = lif_update(aW, syn2[r], mem2[r], nib2[r]);
      if (!last) nib1[r] = lif_update(aV, syn1[r], mem1[r], nib1[r]);

      u64 D0 = __ballot(nib2[r] & 1u), D1 = __ballot(nib2[r] & 2u);
      u64 D2 = __ballot(nib2[r] & 4u), D3 = __ballot(nib2[r] & 8u);
      u64 E0 = __ballot(nib1[r] & 1u), E1 = __ballot(nib1[r] & 2u);
      u64 E2 = __ballot(nib1[r] & 4u), E3 = __ballot(nib1[r] & 8u);
      if (lane < 4) {
        __hip_atomic_store(&m2H[((size_t)s * NB + smp) * NWPS + 4 * x + lane],
                           pack_word(D0, D1, D2, D3, lane), __ATOMIC_RELAXED,
                           __HIP_MEMORY_SCOPE_AGENT);
        if (!last)
          __hip_atomic_store(&m1n[(size_t)smp * NWPS + 4 * x + lane],
                             pack_word(E0, E1, E2, E3, lane), __ATOMIC_RELAXED,
                             __HIP_MEMORY_SCOPE_AGENT);
      }
    }
    __builtin_amdgcn_s_setprio(0);

    if (!last) {
      __syncthreads();   // single merged drain (m2H + m1n)
      if (tid == 0)
        __hip_atomic_store(SLOT(slots, g, x), (u32)(s + 2), __ATOMIC_RELAXED,
                           __HIP_MEMORY_SCOPE_AGENT);
      // shadow: xw prefetch under the poll window
      if ((s & 1) == 0) {
        if constexpr (UXW) {
          int t2 = (s >> 1) + 1;
          if (t2 < 64) {
#pragma unroll
            for (int r = 0; r < SPW; ++r)
              xwN[r] = __builtin_nontemporal_load(
                  (const f32x4*)(XWc + ((size_t)t2 * NB + s0 + r) * HD));
          }
        }
      }
      if (tid == 0) {
        while (true) {
          u32 mn = 0xffffffffu;
#pragma unroll
          for (int x2 = 0; x2 < 8; ++x2) {
            u32 v = __hip_atomic_load(SLOT(slots, g, x2), __ATOMIC_RELAXED,
                                      __HIP_MEMORY_SCOPE_AGENT);
            mn = v < mn ? v : mn;
          }
          if (mn >= (u32)(s + 2)) break;
          __builtin_amdgcn_s_sleep(1);
        }
      }
      __syncthreads();
    }
  }

  // ---- final rendezvous (full fence once) ----
  __syncthreads();
  if (tid == 0) {
    __threadfence();
    __hip_atomic_fetch_add(done, 1u, __ATOMIC_RELEASE, __HIP_MEMORY_SCOPE_AGENT);
    while (__hip_atomic_load(done, __ATOMIC_RELAXED,
                             __HIP_MEMORY_SCOPE_AGENT) < (u32)gridDim.x)
      __builtin_amdgcn_s_sleep(8);
    __threadfence();
  }
  __syncthreads();

  // ---- deferred readout: SPW waves/block, wave = one sample ----
  if (wv < SPW) {
    const int rsmp = blockIdx.x * SPW + wv;
    const float bor = bo[lane];
    float synr = 0.f, memr = 0.f, roprev = 0.f;
    for (int s = 0; s < NSTEPS; ++s) {
      int total = build_list_ro(m2H + ((size_t)s * NB + rsmp) * NWPS, lst, lane);
      float a = bor;
      for (int j0 = 0; j0 < total; j0 += 8) {
        float vv[8];
#pragma unroll
        for (int u = 0; u < 8; ++u) {
          int idx = j0 + u;
          if (idx >= total) idx = j0;
          vv[u] = Wo[(((size_t)lst[idx]) << 6) + lane];
        }
#pragma unroll
        for (int u = 0; u < 8; ++u)
          if (j0 + u < total) a += vv[u];
      }
      float nmemr = DMc * memr + SMc * synr;  // R1 shape
      float nsynr = DSc * synr + a;           // R1 shape
      memr = nmemr;
      synr = nsynr;
      if (s & 1) {
        float v = 0.5f * (roprev + nmemr);
        size_t base = ((size_t)(s >> 1) * NB + rsmp) * 32;
        if (lane < 32) out[base + lane] = v;
        else out[(size_t)64 * NB * 32 + base + (lane - 32)] = v;
      } else {
        roprev = nmemr;
      }
    }
  }
}

extern "C" void kernel_launch(void* const* d_in, const int* in_sizes, int n_in,
                              void* d_out, int out_size, void* d_ws, size_t ws_size,
                              hipStream_t stream) {
  const float* state  = (const float*)d_in[0];
  const float* target = (const float*)d_in[1];
  const float* Wi     = (const float*)d_in[2];
  const float* bi     = (const float*)d_in[3];
  const float* Vr     = (const float*)d_in[4];
  const float* Wf     = (const float*)d_in[5];
  const float* bf     = (const float*)d_in[6];
  const float* Wo     = (const float*)d_in[7];
  const float* bo     = (const float*)d_in[8];
  float* out = (float*)d_out;
  char* wsb = (char*)d_ws;

  const int use_xw = (ws_size >= OFF_XW + SZ_XW) ? 1 : 0;

  // can we co-schedule 2 blocks/CU? (deterministic host-side query)
  int nb = 0;
  if (use_xw)
    (void)hipOccupancyMaxActiveBlocksPerMultiprocessor(&nb, rsnn_coop<1, 1>,
                                                       THREADS, 0);
  else
    (void)hipOccupancyMaxActiveBlocksPerMultiprocessor(&nb, rsnn_coop<1, 0>,
                                                       THREADS, 0);
  const int spw1 = (nb >= 2) ? 1 : 0;

  init_ws<<<128, 256, 0, stream>>>((u64*)(wsb + OFF_M1W), (u32*)(wsb + OFF_SLOT),
                                   (u32*)(wsb + OFF_CNT), (u32*)(wsb + OFF_DONE));
  pack_kernel<<<ROWS, 256, 0, stream>>>(Vr, Wf, (float*)(wsb + OFF_PK));
  if (use_xw)
    xw_kernel<<<dim3(8, 2048), 256, 0, stream>>>(state, target, Wi, bi,
                                                 (float*)(wsb + OFF_XW));

  void* args[] = {(void*)&state, (void*)&target, (void*)&Wi, (void*)&bi,
                  (void*)&Vr, (void*)&Wf, (void*)&bf, (void*)&Wo, (void*)&bo,
                  (void*)&out, (void*)&wsb};
  if (spw1) {
    if (use_xw)
      (void)hipLaunchCooperativeKernel(rsnn_coop<1, 1>, dim3(512), dim3(THREADS),
                                       args, 0, stream);
    else
      (void)hipLaunchCooperativeKernel(rsnn_coop<1, 0>, dim3(512), dim3(THREADS),
                                       args, 0, stream);
  } else {
    if (use_xw)
      (void)hipLaunchCooperativeKernel(rsnn_coop<2, 1>, dim3(256), dim3(THREADS),
                                       args, 0, stream);
    else
      (void)hipLaunchCooperativeKernel(rsnn_coop<2, 0>, dim3(256), dim3(THREADS),
                                       args, 0, stream);
  }
}

// Round 17
// 9374.699 us; speedup vs baseline: 1.1432x; 1.1432x over previous
//
#include <hip/hip_runtime.h>
#include <stdint.h>

// PolicyNetRSNNPB R17 = R16 with the PK slice back to EXACTLY 4.0 MB/XCD.
// Ledger isolation: every FETCH-explosion round (R13-R16, 14-19GB) had
// ROWS=2049 -> slice 4.196MB > 4MB L2 -> cyclic LRU thrash (~100% miss).
// R11 (ROWS=2048, slice 4.00MB) fetched 0.84GB. The zero-pad row was the
// constant poison across all four regressions.
// R17: ROWS=2048, guarded-tail gather (full 8-batches unguarded + one
// guarded tail). Otherwise identical to R16: physical XCD claim, grid 512
// (2 blk/CU, two independent group-chains/CU), slot rendezvous, setprio.
// SPW=2/grid-256 fallback (= R11 geometry). Bit-exact order (absmax 0.0).

typedef unsigned long long u64;
typedef unsigned int u32;
typedef float f32x4 __attribute__((ext_vector_type(4)));

#define NB 512
#define HD 2048
#define ROWS 2048          // EXACTLY 4.0 MB per XCD slice
#define NSTEPS 128
#define THREADS 512
#define COLS 256
#define NWPS 32
#define LSTN 2080          // 8*2080*2B = 33,280B LDS -> 2 blocks/CU possible

#define DMc 0.8187307530779818f
#define DSc 0.6065306597126334f
#define SMc 0.18126924692201818f

// ---- ws layout ----
#define OFF_M1W 0
#define SZ_M1W ((size_t)2 * NB * NWPS * 8)       // 256 KB
#define OFF_M2H (OFF_M1W + SZ_M1W)
#define SZ_M2H ((size_t)NSTEPS * NB * NWPS * 8)  // 16 MB
#define OFF_SLOT (OFF_M2H + SZ_M2H)              // u32 per (g,x), 128B stride
#define SZ_SLOT (64 * 8 * 128)
#define OFF_CNT (OFF_SLOT + SZ_SLOT)             // u32[8] xcd rank counters
#define OFF_DONE (OFF_CNT + 64)
#define OFF_PK (((size_t)(OFF_DONE + 64) + 4194303) & ~(size_t)4194303)
#define SZ_PK ((size_t)8 * ROWS * 512 * 4)       // 32 MB
#define OFF_XW (((OFF_PK + SZ_PK) + 255) & ~(size_t)255)
#define SZ_XW ((size_t)64 * NB * HD * 4)         // 256 MB

#define HWREG_XCC_ID (20 | ((4 - 1) << 11))
#define SLOT(base, g, x) ((base) + ((size_t)((g)*8 + (x)) * 32))

__global__ void init_ws(u64* __restrict__ m1W, u32* __restrict__ slots,
                        u32* __restrict__ cnt, u32* __restrict__ done) {
  int i = blockIdx.x * 256 + threadIdx.x;
  if (i < 2 * NB * NWPS) m1W[i] = 0ULL;
  if (i < 64 * 8 * 32) slots[i] = 0u;
  if (i < 8) cnt[i] = 0u;
  if (i == 0) *done = 0u;
}

// PK[x][k][0..255]=Vr[k][x*256+..], [256..511]=Wf[k][..]
__global__ __launch_bounds__(256) void pack_kernel(
    const float* __restrict__ Vr, const float* __restrict__ Wf,
    float* __restrict__ PK) {
  const int k = blockIdx.x;
  const int tid = threadIdx.x;
  for (int c = tid; c < HD; c += 256) {
    int x = c >> 8, cc = c & 255;
    size_t base = ((size_t)x * ROWS + k) * 512;
    __builtin_nontemporal_store(Vr[(size_t)k * HD + c], &PK[base + cc]);
    __builtin_nontemporal_store(Wf[(size_t)k * HD + c], &PK[base + 256 + cc]);
  }
}

// XW[t*NB+n][h] = bi[h] + x(t,n,:) @ Wi
__global__ __launch_bounds__(256) void xw_kernel(
    const float* __restrict__ state, const float* __restrict__ target,
    const float* __restrict__ Wi, const float* __restrict__ bi,
    float* __restrict__ XW) {
  __shared__ float xl[16][128];
  const int tid = threadIdx.x;
  const int col = blockIdx.x * 256 + tid;
  const int r0 = blockIdx.y * 16;

  for (int idx = tid; idx < 16 * 128; idx += 256) {
    int r = idx >> 7, k = idx & 127;
    int gg = r0 + r;
    int t = gg >> 9, n = gg & 511;
    float v = (k < 64) ? state[((size_t)(t * NB + n)) * 64 + k]
                       : target[((size_t)(t * NB + n)) * 64 + (k - 64)];
    xl[r][k] = v;
  }
  __syncthreads();

  float acc[16];
  float b = bi[col];
#pragma unroll
  for (int r = 0; r < 16; ++r) acc[r] = b;
  for (int k = 0; k < 128; ++k) {
    float w = Wi[(size_t)k * HD + col];
#pragma unroll
    for (int r = 0; r < 16; ++r) acc[r] = fmaf(xl[r][k], w, acc[r]);
  }
#pragma unroll
  for (int r = 0; r < 16; ++r)
    __builtin_nontemporal_store(acc[r], &XW[(size_t)(r0 + r) * HD + col]);
}

__device__ __forceinline__ u64 spread4(u64 x) {
  x &= 0xffffULL;
  x = (x | (x << 24)) & 0x000000FF000000FFULL;
  x = (x | (x << 12)) & 0x000F000F000F000FULL;
  x = (x | (x << 6))  & 0x0303030303030303ULL;
  x = (x | (x << 3))  & 0x1111111111111111ULL;
  return x;
}

__device__ __forceinline__ u64 pack_word(u64 B0, u64 B1, u64 B2, u64 B3, int q) {
  int sh = q * 16;
  return spread4(B0 >> sh) | (spread4(B1 >> sh) << 1) |
         (spread4(B2 >> sh) << 2) | (spread4(B3 >> sh) << 3);
}

// one-sample list build from MALL masks; ascending k. Returns true count.
__device__ __forceinline__ int build_one(const u64* __restrict__ mw,
                                         uint16_t* __restrict__ lst, int lane) {
  u64 w = 0ULL;
  if (lane < NWPS)
    w = __hip_atomic_load((u64*)&mw[lane], __ATOMIC_RELAXED,
                          __HIP_MEMORY_SCOPE_AGENT);
  int pc = __popcll(w);
  int pre = pc;
#pragma unroll
  for (int off = 1; off < 64; off <<= 1) {
    int v = __shfl_up(pre, off);
    if (lane >= off) pre += v;
  }
  int excl = pre - pc;
  int total = __shfl(pre, 63);
  int kb = lane << 6;
  while (w) {
    int b = __builtin_ctzll(w);
    w &= w - 1;
    lst[excl++] = (uint16_t)(kb + b);
  }
  asm volatile("s_waitcnt lgkmcnt(0)" ::: "memory");
  return total;
}

// readout-tail list build (plain loads)
__device__ __forceinline__ int build_list_ro(const u64* __restrict__ mwords,
                                             uint16_t* __restrict__ lstw,
                                             int lane) {
  u64 w = (lane < NWPS) ? mwords[lane] : 0ULL;
  int pc = __popcll(w);
  int pre = pc;
#pragma unroll
  for (int off = 1; off < 64; off <<= 1) {
    int v = __shfl_up(pre, off);
    if (lane >= off) pre += v;
  }
  int excl = pre - pc;
  int total = __shfl(pre, 63);
  int kb = lane << 6;
  while (w) {
    int b = __builtin_ctzll(w);
    w &= w - 1;
    lstw[excl++] = (uint16_t)(kb + b);
  }
  asm volatile("s_waitcnt lgkmcnt(0)" ::: "memory");
  return total;
}

__device__ __forceinline__ u32 lif_update(const float acc[4], float syn[4],
                                          float mem[4], u32 snib) {
  u32 nib = 0;
#pragma unroll
  for (int j = 0; j < 4; ++j) {
    float so = (float)((snib >> j) & 1u);
    float nmem = (DMc * mem[j] + SMc * syn[j]) * (1.0f - so);  // R1 shape
    float nsyn = DSc * syn[j] + acc[j];                         // R1 shape
    mem[j] = nmem;
    syn[j] = nsyn;
    if ((nmem - 1.0f) > 0.0f) nib |= (1u << j);
  }
  return nib;
}

// dual gather: full 8-batches unguarded; single guarded tail batch.
// Ascending k; separate accumulators (bit-exact).
__device__ __forceinline__ void gather_one(const float* __restrict__ PKb,
                                           const uint16_t* __restrict__ lst,
                                           int total, float aV[4], float aW[4]) {
  const int full = total & ~7;
  for (int j0 = 0; j0 < full; j0 += 8) {
    f32x4 v[8], w8[8];
#pragma unroll
    for (int u = 0; u < 8; ++u) {
      size_t off = ((size_t)lst[j0 + u]) << 9;
      v[u] = *(const f32x4*)(PKb + off);
      w8[u] = *(const f32x4*)(PKb + off + 256);
    }
#pragma unroll
    for (int u = 0; u < 8; ++u) {
      aV[0] += v[u].x; aV[1] += v[u].y; aV[2] += v[u].z; aV[3] += v[u].w;
      aW[0] += w8[u].x; aW[1] += w8[u].y; aW[2] += w8[u].z; aW[3] += w8[u].w;
    }
  }
  if (full < total) {
    f32x4 v[8], w8[8];
#pragma unroll
    for (int u = 0; u < 8; ++u) {
      int idx = full + u;
      if (idx >= total) idx = full;
      size_t off = ((size_t)lst[idx]) << 9;
      v[u] = *(const f32x4*)(PKb + off);
      w8[u] = *(const f32x4*)(PKb + off + 256);
    }
#pragma unroll
    for (int u = 0; u < 8; ++u)
      if (full + u < total) {
        aV[0] += v[u].x; aV[1] += v[u].y; aV[2] += v[u].z; aV[3] += v[u].w;
        aW[0] += w8[u].x; aW[1] += w8[u].y; aW[2] += w8[u].z; aW[3] += w8[u].w;
      }
  }
}

// SPW = samples per wave (1: grid 512, 2 blk/CU, rank&63; 2: grid 256, rank&31)
template <int SPW, int UXW>
__global__ __launch_bounds__(THREADS, 2) void rsnn_coop(
    const float* __restrict__ state, const float* __restrict__ target,
    const float* __restrict__ Wi, const float* __restrict__ bi,
    const float* __restrict__ Vr, const float* __restrict__ Wf,
    const float* __restrict__ bf, const float* __restrict__ Wo,
    const float* __restrict__ bo, float* __restrict__ out,
    char* __restrict__ wsb) {
  __shared__ uint16_t lst_s[8][LSTN];   // 33,280 B
  __shared__ int sh_x, sh_g;

  u64* m1W = (u64*)(wsb + OFF_M1W);
  u64* m2H = (u64*)(wsb + OFF_M2H);
  u32* slots = (u32*)(wsb + OFF_SLOT);
  u32* cnt = (u32*)(wsb + OFF_CNT);
  u32* done = (u32*)(wsb + OFF_DONE);
  const float* PK = (const float*)(wsb + OFF_PK);
  const float* XW = (const float*)(wsb + OFF_XW);

  const int tid = threadIdx.x;
  const int wv = tid >> 6;      // 0..7
  const int lane = tid & 63;    // lane = 4 columns

  // physical XCD claim: slice = real XCD; rank = group id
  if (tid == 0) {
    int xx = __builtin_amdgcn_s_getreg(HWREG_XCC_ID) & 7;
    sh_x = xx;
    sh_g = atomicAdd(&cnt[xx], 1u) & (SPW == 1 ? 63 : 31);
  }
  __syncthreads();
  const int x = sh_x;
  const int g = sh_g;
  const int c0 = x * COLS;
  const int s0 = (g * 8 + wv) * SPW;     // first sample of this wave

  uint16_t* lst = &lst_s[wv][0];

  float bir[4], bfr[4];
#pragma unroll
  for (int j = 0; j < 4; ++j) {
    bir[j] = bi[c0 + lane * 4 + j];
    bfr[j] = bf[c0 + lane * 4 + j];
  }

  float syn1[SPW][4], mem1[SPW][4], syn2[SPW][4], mem2[SPW][4];
#pragma unroll
  for (int r = 0; r < SPW; ++r)
#pragma unroll
    for (int j = 0; j < 4; ++j) {
      syn1[r][j] = 0.f; mem1[r][j] = 0.f; syn2[r][j] = 0.f; mem2[r][j] = 0.f;
    }
  u32 nib1[SPW], nib2[SPW];
#pragma unroll
  for (int r = 0; r < SPW; ++r) { nib1[r] = 0u; nib2[r] = 0u; }
  float xw[SPW][4];
  f32x4 xwN[SPW];

  const float* PKb = PK + (size_t)x * ROWS * 512 + lane * 4;
  const float* XWc = XW + c0 + lane * 4;

  // fallback xw (k-ascending fmaf from global Wi)
  auto compute_xw = [&](int t2, int r) {
#pragma unroll
    for (int j = 0; j < 4; ++j) xw[r][j] = bir[j];
#pragma unroll
    for (int half = 0; half < 2; ++half) {
      const float* p =
          (half ? target : state) + ((size_t)t2 * NB + s0 + r) * 64;
      for (int q = 0; q < 16; ++q) {
        f32x4 xq = *(const f32x4*)(p + 4 * q);
        float xv[4] = {xq.x, xq.y, xq.z, xq.w};
#pragma unroll
        for (int kj = 0; kj < 4; ++kj) {
          const f32x4 w4 = *(const f32x4*)&Wi[(size_t)(half * 64 + 4 * q + kj) *
                                                  HD + c0 + lane * 4];
          xw[r][0] = fmaf(xv[kj], w4.x, xw[r][0]);
          xw[r][1] = fmaf(xv[kj], w4.y, xw[r][1]);
          xw[r][2] = fmaf(xv[kj], w4.z, xw[r][2]);
          xw[r][3] = fmaf(xv[kj], w4.w, xw[r][3]);
        }
      }
    }
  };

  // ---- prologue: xw(0); LIF1(0); publish m1(0); barrier; arrive 1; poll ----
#pragma unroll
  for (int r = 0; r < SPW; ++r) {
    if constexpr (UXW) {
      f32x4 a = __builtin_nontemporal_load(
          (const f32x4*)(XWc + (size_t)(s0 + r) * HD));
      xw[r][0] = a.x; xw[r][1] = a.y; xw[r][2] = a.z; xw[r][3] = a.w;
    } else {
      compute_xw(0, r);
    }
    nib1[r] = lif_update(xw[r], syn1[r], mem1[r], 0u);
    u64 E0 = __ballot(nib1[r] & 1u), E1 = __ballot(nib1[r] & 2u);
    u64 E2 = __ballot(nib1[r] & 4u), E3 = __ballot(nib1[r] & 8u);
    if (lane < 4)
      __hip_atomic_store(&m1W[(size_t)(s0 + r) * NWPS + 4 * x + lane],
                         pack_word(E0, E1, E2, E3, lane), __ATOMIC_RELAXED,
                         __HIP_MEMORY_SCOPE_AGENT);
  }
  __syncthreads();
  if (tid == 0)
    __hip_atomic_store(SLOT(slots, g, x), 1u, __ATOMIC_RELAXED,
                       __HIP_MEMORY_SCOPE_AGENT);
  __syncthreads();
  if (tid == 0) {
    while (true) {
      u32 mn = 0xffffffffu;
#pragma unroll
      for (int x2 = 0; x2 < 8; ++x2) {
        u32 v = __hip_atomic_load(SLOT(slots, g, x2), __ATOMIC_RELAXED,
                                  __HIP_MEMORY_SCOPE_AGENT);
        mn = v < mn ? v : mn;
      }
      if (mn >= 1u) break;
      __builtin_amdgcn_s_sleep(1);
    }
  }
  __syncthreads();

  // ---- main loop: step s gathers with m1(s); xw holds t=(s+1)>>1 ----
  for (int s = 0; s < NSTEPS; ++s) {
    const bool last = (s == NSTEPS - 1);
    if (s & 1) {
#pragma unroll
      for (int r = 0; r < SPW; ++r) {
        if constexpr (UXW) {
          xw[r][0] = xwN[r].x; xw[r][1] = xwN[r].y;
          xw[r][2] = xwN[r].z; xw[r][3] = xwN[r].w;
        } else {
          if (s + 1 < NSTEPS) compute_xw((s + 1) >> 1, r);
        }
      }
    }

    const u64* m1cur = m1W + (size_t)(s & 1) * NB * NWPS;
    u64* m1n = m1W + (size_t)((s + 1) & 1) * NB * NWPS;

    __builtin_amdgcn_s_setprio(1);
#pragma unroll
    for (int r = 0; r < SPW; ++r) {
      const int smp = s0 + r;
      int total = build_one(m1cur + (size_t)smp * NWPS, lst, lane);
      float aV[4] = {xw[r][0], xw[r][1], xw[r][2], xw[r][3]};
      float aW[4] = {bfr[0], bfr[1], bfr[2], bfr[3]};
      gather_one(PKb, lst, total, aV, aW);

      nib2[r] = lif_update(aW, syn2[r], mem2[r], nib2[r]);
      if (!last) nib1[r] = lif_update(aV, syn1[r], mem1[r], nib1[r]);

      u64 D0 = __ballot(nib2[r] & 1u), D1 = __ballot(nib2[r] & 2u);
      u64 D2 = __ballot(nib2[r] & 4u), D3 = __ballot(nib2[r] & 8u);
      u64 E0 = __ballot(nib1[r] & 1u), E1 = __ballot(nib1[r] & 2u);
      u64 E2 = __ballot(nib1[r] & 4u), E3 = __ballot(nib1[r] & 8u);
      if (lane < 4) {
        __hip_atomic_store(&m2H[((size_t)s * NB + smp) * NWPS + 4 * x + lane],
                           pack_word(D0, D1, D2, D3, lane), __ATOMIC_RELAXED,
                           __HIP_MEMORY_SCOPE_AGENT);
        if (!last)
          __hip_atomic_store(&m1n[(size_t)smp * NWPS + 4 * x + lane],
                             pack_word(E0, E1, E2, E3, lane), __ATOMIC_RELAXED,
                             __HIP_MEMORY_SCOPE_AGENT);
      }
    }
    __builtin_amdgcn_s_setprio(0);

    if (!last) {
      __syncthreads();   // single merged drain (m2H + m1n)
      if (tid == 0)
        __hip_atomic_store(SLOT(slots, g, x), (u32)(s + 2), __ATOMIC_RELAXED,
                           __HIP_MEMORY_SCOPE_AGENT);
      // shadow: xw prefetch under the poll window
      if ((s & 1) == 0) {
        if constexpr (UXW) {
          int t2 = (s >> 1) + 1;
          if (t2 < 64) {
#pragma unroll
            for (int r = 0; r < SPW; ++r)
              xwN[r] = __builtin_nontemporal_load(
                  (const f32x4*)(XWc + ((size_t)t2 * NB + s0 + r) * HD));
          }
        }
      }
      if (tid == 0) {
        while (true) {
          u32 mn = 0xffffffffu;
#pragma unroll
          for (int x2 = 0; x2 < 8; ++x2) {
            u32 v = __hip_atomic_load(SLOT(slots, g, x2), __ATOMIC_RELAXED,
                                      __HIP_MEMORY_SCOPE_AGENT);
            mn = v < mn ? v : mn;
          }
          if (mn >= (u32)(s + 2)) break;
          __builtin_amdgcn_s_sleep(1);
        }
      }
      __syncthreads();
    }
  }

  // ---- final rendezvous (full fence once) ----
  __syncthreads();
  if (tid == 0) {
    __threadfence();
    __hip_atomic_fetch_add(done, 1u, __ATOMIC_RELEASE, __HIP_MEMORY_SCOPE_AGENT);
    while (__hip_atomic_load(done, __ATOMIC_RELAXED,
                             __HIP_MEMORY_SCOPE_AGENT) < (u32)gridDim.x)
      __builtin_amdgcn_s_sleep(8);
    __threadfence();
  }
  __syncthreads();

  // ---- deferred readout: SPW waves/block, wave = one sample ----
  if (wv < SPW) {
    const int rsmp = blockIdx.x * SPW + wv;
    const float bor = bo[lane];
    float synr = 0.f, memr = 0.f, roprev = 0.f;
    for (int s = 0; s < NSTEPS; ++s) {
      int total = build_list_ro(m2H + ((size_t)s * NB + rsmp) * NWPS, lst, lane);
      float a = bor;
      for (int j0 = 0; j0 < total; j0 += 8) {
        float vv[8];
#pragma unroll
        for (int u = 0; u < 8; ++u) {
          int idx = j0 + u;
          if (idx >= total) idx = j0;
          vv[u] = Wo[(((size_t)lst[idx]) << 6) + lane];
        }
#pragma unroll
        for (int u = 0; u < 8; ++u)
          if (j0 + u < total) a += vv[u];
      }
      float nmemr = DMc * memr + SMc * synr;  // R1 shape
      float nsynr = DSc * synr + a;           // R1 shape
      memr = nmemr;
      synr = nsynr;
      if (s & 1) {
        float v = 0.5f * (roprev + nmemr);
        size_t base = ((size_t)(s >> 1) * NB + rsmp) * 32;
        if (lane < 32) out[base + lane] = v;
        else out[(size_t)64 * NB * 32 + base + (lane - 32)] = v;
      } else {
        roprev = nmemr;
      }
    }
  }
}

extern "C" void kernel_launch(void* const* d_in, const int* in_sizes, int n_in,
                              void* d_out, int out_size, void* d_ws, size_t ws_size,
                              hipStream_t stream) {
  const float* state  = (const float*)d_in[0];
  const float* target = (const float*)d_in[1];
  const float* Wi     = (const float*)d_in[2];
  const float* bi     = (const float*)d_in[3];
  const float* Vr     = (const float*)d_in[4];
  const float* Wf     = (const float*)d_in[5];
  const float* bf     = (const float*)d_in[6];
  const float* Wo     = (const float*)d_in[7];
  const float* bo     = (const float*)d_in[8];
  float* out = (float*)d_out;
  char* wsb = (char*)d_ws;

  const int use_xw = (ws_size >= OFF_XW + SZ_XW) ? 1 : 0;

  // can we co-schedule 2 blocks/CU? (deterministic host-side query)
  int nb = 0;
  if (use_xw)
    (void)hipOccupancyMaxActiveBlocksPerMultiprocessor(&nb, rsnn_coop<1, 1>,
                                                       THREADS, 0);
  else
    (void)hipOccupancyMaxActiveBlocksPerMultiprocessor(&nb, rsnn_coop<1, 0>,
                                                       THREADS, 0);
  const int spw1 = (nb >= 2) ? 1 : 0;

  init_ws<<<128, 256, 0, stream>>>((u64*)(wsb + OFF_M1W), (u32*)(wsb + OFF_SLOT),
                                   (u32*)(wsb + OFF_CNT), (u32*)(wsb + OFF_DONE));
  pack_kernel<<<ROWS, 256, 0, stream>>>(Vr, Wf, (float*)(wsb + OFF_PK));
  if (use_xw)
    xw_kernel<<<dim3(8, 2048), 256, 0, stream>>>(state, target, Wi, bi,
                                                 (float*)(wsb + OFF_XW));

  void* args[] = {(void*)&state, (void*)&target, (void*)&Wi, (void*)&bi,
                  (void*)&Vr, (void*)&Wf, (void*)&bf, (void*)&Wo, (void*)&bo,
                  (void*)&out, (void*)&wsb};
  if (spw1) {
    if (use_xw)
      (void)hipLaunchCooperativeKernel(rsnn_coop<1, 1>, dim3(512), dim3(THREADS),
                                       args, 0, stream);
    else
      (void)hipLaunchCooperativeKernel(rsnn_coop<1, 0>, dim3(512), dim3(THREADS),
                                       args, 0, stream);
  } else {
    if (use_xw)
      (void)hipLaunchCooperativeKernel(rsnn_coop<2, 1>, dim3(256), dim3(THREADS),
                                       args, 0, stream);
    else
      (void)hipLaunchCooperativeKernel(rsnn_coop<2, 0>, dim3(256), dim3(THREADS),
                                       args, 0, stream);
  }
}

// Round 18
// 3450.282 us; speedup vs baseline: 3.1062x; 2.7171x over previous
//
#include <hip/hip_runtime.h>
#include <stdint.h>

// PolicyNetRSNNPB R18 = R11 (best: 3578us, FETCH 0.84GB) + unguarded-fastpath
// gather. R13-R17 post-mortem: every added-concurrency variant (1024thr, 2
// blk/CU) crosses the exactly-4MB/XCD L2 knife edge (cyclic LRU thrash) or
// the 64-VGPR cliff; R11's geometry (256 blk x 512thr, 1 blk/CU, wave = 2
// samples, physical XCD claim) is the stable optimum. Single change vs R11:
// gather_ab runs full batches of BOTH samples unguarded (no idx clamps, no
// masked adds) and guards only the tail batches. Same ascending add order,
// separate accumulators -> bit-exact (absmax 0.0 preserved).

typedef unsigned long long u64;
typedef unsigned int u32;
typedef float f32x4 __attribute__((ext_vector_type(4)));

#define NB 512
#define HD 2048
#define NSTEPS 128
#define THREADS 512
#define NBLK 256
#define COLS 256
#define SPB 16
#define NWPS 32
#define LSTN 832

#define DMc 0.8187307530779818f
#define DSc 0.6065306597126334f
#define SMc 0.18126924692201818f

// ---- ws layout ----
#define OFF_M1W 0
#define SZ_M1W ((size_t)2 * NB * NWPS * 8)       // 256 KB
#define OFF_M2H (OFF_M1W + SZ_M1W)
#define SZ_M2H ((size_t)NSTEPS * NB * NWPS * 8)  // 16 MB
#define OFF_FLAG (OFF_M2H + SZ_M2H)
#define SZ_FLAG (32 * 32 * 4)
#define OFF_CNT (OFF_FLAG + SZ_FLAG)
#define OFF_DONE (OFF_CNT + 64)
#define OFF_PK (((size_t)(OFF_DONE + 4) + 4194303) & ~(size_t)4194303)
#define SZ_PK ((size_t)8 * HD * 512 * 4)         // 32 MB (exactly 4.0MB/XCD)
#define OFF_XW (((OFF_PK + SZ_PK) + 255) & ~(size_t)255)
#define SZ_XW ((size_t)64 * NB * HD * 4)         // 256 MB

#define HWREG_XCC_ID (20 | ((4 - 1) << 11))

__global__ void init_ws(u64* __restrict__ m1W, u32* __restrict__ flags,
                        u32* __restrict__ cnt, u32* __restrict__ done) {
  int i = blockIdx.x * 256 + threadIdx.x;
  if (i < 2 * NB * NWPS) m1W[i] = 0ULL;
  if (i < 32 * 32) flags[i] = 0u;
  if (i < 8) cnt[i] = 0u;
  if (i == 0) *done = 0u;
}

// PK[xcd][k][0..255]=Vr[k][xcd*256+..], [256..511]=Wf[k][..]
__global__ __launch_bounds__(256) void pack_kernel(
    const float* __restrict__ Vr, const float* __restrict__ Wf,
    float* __restrict__ PK) {
  const int k = blockIdx.x;
  const int tid = threadIdx.x;
  for (int c = tid; c < HD; c += 256) {
    int xcd = c >> 8, cc = c & 255;
    size_t base = ((size_t)xcd * HD + k) * 512;
    __builtin_nontemporal_store(Vr[(size_t)k * HD + c], &PK[base + cc]);
    __builtin_nontemporal_store(Wf[(size_t)k * HD + c], &PK[base + 256 + cc]);
  }
}

// XW[t*NB+n][h] = bi[h] + x(t,n,:) @ Wi
__global__ __launch_bounds__(256) void xw_kernel(
    const float* __restrict__ state, const float* __restrict__ target,
    const float* __restrict__ Wi, const float* __restrict__ bi,
    float* __restrict__ XW) {
  __shared__ float xl[16][128];
  const int tid = threadIdx.x;
  const int col = blockIdx.x * 256 + tid;
  const int r0 = blockIdx.y * 16;

  for (int idx = tid; idx < 16 * 128; idx += 256) {
    int r = idx >> 7, k = idx & 127;
    int gg = r0 + r;
    int t = gg >> 9, n = gg & 511;
    float v = (k < 64) ? state[((size_t)(t * NB + n)) * 64 + k]
                       : target[((size_t)(t * NB + n)) * 64 + (k - 64)];
    xl[r][k] = v;
  }
  __syncthreads();

  float acc[16];
  float b = bi[col];
#pragma unroll
  for (int r = 0; r < 16; ++r) acc[r] = b;
  for (int k = 0; k < 128; ++k) {
    float w = Wi[(size_t)k * HD + col];
#pragma unroll
    for (int r = 0; r < 16; ++r) acc[r] = fmaf(xl[r][k], w, acc[r]);
  }
#pragma unroll
  for (int r = 0; r < 16; ++r)
    __builtin_nontemporal_store(acc[r], &XW[(size_t)(r0 + r) * HD + col]);
}

// bit i of low-16 -> bit 4i
__device__ __forceinline__ u64 spread4(u64 x) {
  x &= 0xffffULL;
  x = (x | (x << 24)) & 0x000000FF000000FFULL;
  x = (x | (x << 12)) & 0x000F000F000F000FULL;
  x = (x | (x << 6))  & 0x0303030303030303ULL;
  x = (x | (x << 3))  & 0x1111111111111111ULL;
  return x;
}

__device__ __forceinline__ u64 pack_word(u64 B0, u64 B1, u64 B2, u64 B3, int q) {
  int sh = q * 16;
  return spread4(B0 >> sh) | (spread4(B1 >> sh) << 1) |
         (spread4(B2 >> sh) << 2) | (spread4(B3 >> sh) << 3);
}

// merged A+B list build (one atomic round, half-wave scans)
__device__ __forceinline__ void build_ab(const u64* __restrict__ mA,
                                         const u64* __restrict__ mB,
                                         uint16_t* __restrict__ lstA,
                                         uint16_t* __restrict__ lstB,
                                         int lane, int& totA, int& totB) {
  const int hf = lane >> 5, wl = lane & 31;
  const u64* src = hf ? mB : mA;
  u64 w = __hip_atomic_load(src + wl, __ATOMIC_RELAXED,
                            __HIP_MEMORY_SCOPE_AGENT);
  int pc = __popcll(w);
  int pre = pc;
#pragma unroll
  for (int off = 1; off < 32; off <<= 1) {
    int v = __shfl_up(pre, off, 32);
    if (wl >= off) pre += v;
  }
  int excl = pre - pc;
  totA = __shfl(pre, 31);
  totB = __shfl(pre, 63);
  uint16_t* lw = hf ? lstB : lstA;
  int kb = wl << 6;
  while (w) {
    int b = __builtin_ctzll(w);
    w &= w - 1;
    if (excl < LSTN) lw[excl] = (uint16_t)(kb + b);
    ++excl;
  }
  asm volatile("s_waitcnt lgkmcnt(0)" ::: "memory");
  totA = totA < LSTN ? totA : LSTN;
  totB = totB < LSTN ? totB : LSTN;
}

// full-wave list build (readout tail; plain loads)
__device__ __forceinline__ int build_list_ro(const u64* __restrict__ mwords,
                                             uint16_t* __restrict__ lstw,
                                             int lane) {
  u64 w = (lane < NWPS) ? mwords[lane] : 0ULL;
  int pc = __popcll(w);
  int pre = pc;
#pragma unroll
  for (int off = 1; off < 64; off <<= 1) {
    int v = __shfl_up(pre, off);
    if (lane >= off) pre += v;
  }
  int excl = pre - pc;
  int total = __shfl(pre, 63);
  int kb = lane << 6;
  while (w) {
    int b = __builtin_ctzll(w);
    w &= w - 1;
    if (excl < LSTN) lstw[excl] = (uint16_t)(kb + b);
    ++excl;
  }
  asm volatile("s_waitcnt lgkmcnt(0)" ::: "memory");
  return total < LSTN ? total : LSTN;
}

__device__ __forceinline__ u32 lif_update(const float acc[4], float syn[4],
                                          float mem[4], u32 snib) {
  u32 nib = 0;
#pragma unroll
  for (int j = 0; j < 4; ++j) {
    float so = (float)((snib >> j) & 1u);
    float nmem = (DMc * mem[j] + SMc * syn[j]) * (1.0f - so);  // R1 shape
    float nsyn = DSc * syn[j] + acc[j];                         // R1 shape
    mem[j] = nmem;
    syn[j] = nsyn;
    if ((nmem - 1.0f) > 0.0f) nib |= (1u << j);
  }
  return nib;
}

// A+B interleaved dual gather: full batches of BOTH samples unguarded (the
// common case); guarded R11-style batches only for the tail. Ascending k per
// sample, separate accumulators -> bit-exact.
__device__ __forceinline__ void gather_ab(const float* __restrict__ PKb,
                                          const uint16_t* __restrict__ lstA,
                                          int totA,
                                          const uint16_t* __restrict__ lstB,
                                          int totB, float aVA[4], float aWA[4],
                                          float aVB[4], float aWB[4]) {
  const int mn = totA < totB ? totA : totB;
  const int mx = totA > totB ? totA : totB;
  const int fullBoth = mn & ~7;

  int j0 = 0;
  // fast path: both samples have a full batch -> zero guards
  for (; j0 < fullBoth; j0 += 8) {
    f32x4 va[8], wa[8], vb[8], wb[8];
#pragma unroll
    for (int u = 0; u < 8; ++u) {
      size_t offA = ((size_t)lstA[j0 + u]) << 9;
      va[u] = *(const f32x4*)(PKb + offA);
      wa[u] = *(const f32x4*)(PKb + offA + 256);
    }
#pragma unroll
    for (int u = 0; u < 8; ++u) {
      size_t offB = ((size_t)lstB[j0 + u]) << 9;
      vb[u] = *(const f32x4*)(PKb + offB);
      wb[u] = *(const f32x4*)(PKb + offB + 256);
    }
#pragma unroll
    for (int u = 0; u < 8; ++u) {
      aVA[0] += va[u].x; aVA[1] += va[u].y; aVA[2] += va[u].z; aVA[3] += va[u].w;
      aWA[0] += wa[u].x; aWA[1] += wa[u].y; aWA[2] += wa[u].z; aWA[3] += wa[u].w;
    }
#pragma unroll
    for (int u = 0; u < 8; ++u) {
      aVB[0] += vb[u].x; aVB[1] += vb[u].y; aVB[2] += vb[u].z; aVB[3] += vb[u].w;
      aWB[0] += wb[u].x; aWB[1] += wb[u].y; aWB[2] += wb[u].z; aWB[3] += wb[u].w;
    }
  }
  // tail: guarded (R11 form)
  for (; j0 < mx; j0 += 8) {
    f32x4 va[8], wa[8], vb[8], wb[8];
#pragma unroll
    for (int u = 0; u < 8; ++u) {
      int ia = j0 + u;
      if (ia >= totA) ia = 0;
      size_t offA = ((size_t)lstA[ia]) << 9;
      va[u] = *(const f32x4*)(PKb + offA);
      wa[u] = *(const f32x4*)(PKb + offA + 256);
    }
#pragma unroll
    for (int u = 0; u < 8; ++u) {
      int ib = j0 + u;
      if (ib >= totB) ib = 0;
      size_t offB = ((size_t)lstB[ib]) << 9;
      vb[u] = *(const f32x4*)(PKb + offB);
      wb[u] = *(const f32x4*)(PKb + offB + 256);
    }
#pragma unroll
    for (int u = 0; u < 8; ++u)
      if (j0 + u < totA) {
        aVA[0] += va[u].x; aVA[1] += va[u].y; aVA[2] += va[u].z; aVA[3] += va[u].w;
        aWA[0] += wa[u].x; aWA[1] += wa[u].y; aWA[2] += wa[u].z; aWA[3] += wa[u].w;
      }
#pragma unroll
    for (int u = 0; u < 8; ++u)
      if (j0 + u < totB) {
        aVB[0] += vb[u].x; aVB[1] += vb[u].y; aVB[2] += vb[u].z; aVB[3] += vb[u].w;
        aWB[0] += wb[u].x; aWB[1] += wb[u].y; aWB[2] += wb[u].z; aWB[3] += wb[u].w;
      }
  }
}

template <int UXW>
__global__ __launch_bounds__(THREADS, 2) void rsnn_coop(
    const float* __restrict__ state, const float* __restrict__ target,
    const float* __restrict__ Wi, const float* __restrict__ bi,
    const float* __restrict__ Vr, const float* __restrict__ Wf,
    const float* __restrict__ bf, const float* __restrict__ Wo,
    const float* __restrict__ bo, float* __restrict__ out,
    char* __restrict__ wsb) {
  __shared__ float Wi_s[128 * COLS];      // 128 KB (fallback xw; pins 1 blk/CU)
  __shared__ uint16_t lstA_s[8][LSTN];    // 13 KB
  __shared__ uint16_t lstB_s[8][LSTN];    // 13 KB
  __shared__ int sh_xcd, sh_rank;

  u64* m1W = (u64*)(wsb + OFF_M1W);
  u64* m2H = (u64*)(wsb + OFF_M2H);
  u32* flags = (u32*)(wsb + OFF_FLAG);
  u32* cnt = (u32*)(wsb + OFF_CNT);
  u32* done = (u32*)(wsb + OFF_DONE);
  const float* PK = (const float*)(wsb + OFF_PK);
  const float* XW = (const float*)(wsb + OFF_XW);

  const int tid = threadIdx.x;
  const int wv = tid >> 6;      // wave = 2 samples
  const int lane = tid & 63;    // lane = 4 columns

  if (tid == 0) {
    int x = __builtin_amdgcn_s_getreg(HWREG_XCC_ID) & 7;
    sh_xcd = x;
    sh_rank = atomicAdd(&cnt[x], 1u) & 31;
  }
  __syncthreads();
  const int xcd = sh_xcd;
  const int g = sh_rank;
  const int c0 = xcd * COLS;
  const int sA = g * SPB + wv * 2, sB = sA + 1;

  if constexpr (!UXW) {
    for (int i = tid; i < 128 * COLS; i += THREADS) {
      int k = i >> 8, c = i & 255;
      Wi_s[i] = Wi[(size_t)k * HD + c0 + c];
    }
  }
  uint16_t* lstA = &lstA_s[wv][0];
  uint16_t* lstB = &lstB_s[wv][0];
  if (lane == 0) { lstA[0] = 0; lstB[0] = 0; }   // guard rows for clamped loads

  float bir[4], bfr[4];
#pragma unroll
  for (int j = 0; j < 4; ++j) {
    bir[j] = bi[c0 + lane * 4 + j];
    bfr[j] = bf[c0 + lane * 4 + j];
  }

  float syn1A[4], mem1A[4], syn2A[4], mem2A[4];
  float syn1B[4], mem1B[4], syn2B[4], mem2B[4];
#pragma unroll
  for (int j = 0; j < 4; ++j) {
    syn1A[j] = 0.f; mem1A[j] = 0.f; syn2A[j] = 0.f; mem2A[j] = 0.f;
    syn1B[j] = 0.f; mem1B[j] = 0.f; syn2B[j] = 0.f; mem2B[j] = 0.f;
  }
  u32 nib1A = 0u, nib1B = 0u, nib2A = 0u, nib2B = 0u;
  float xwA[4], xwB[4];
  f32x4 xwNA, xwNB;

  const float* PKb = PK + (size_t)xcd * HD * 512 + lane * 4;
  const float* XWc = XW + c0 + lane * 4;
  u32* myflag = &flags[g * 32];

  __syncthreads();  // Wi_s / lst guards ready

  // xw(t) for A,B from Wi_s (k-ascending fmaf; fallback only)
  auto compute_xw = [&](int t2) {
#pragma unroll
    for (int j = 0; j < 4; ++j) { xwA[j] = bir[j]; xwB[j] = bir[j]; }
#pragma unroll
    for (int half = 0; half < 2; ++half) {
      const float* pA = (half ? target : state) + ((size_t)t2 * NB + sA) * 64;
      const float* pB = (half ? target : state) + ((size_t)t2 * NB + sB) * 64;
      for (int q = 0; q < 16; ++q) {
        f32x4 xa = *(const f32x4*)(pA + 4 * q);
        f32x4 xb = *(const f32x4*)(pB + 4 * q);
        float xav[4] = {xa.x, xa.y, xa.z, xa.w};
        float xbv[4] = {xb.x, xb.y, xb.z, xb.w};
#pragma unroll
        for (int kj = 0; kj < 4; ++kj) {
          const f32x4 w4 =
              *(const f32x4*)&Wi_s[(half * 64 + 4 * q + kj) * COLS + lane * 4];
          xwA[0] = fmaf(xav[kj], w4.x, xwA[0]);
          xwA[1] = fmaf(xav[kj], w4.y, xwA[1]);
          xwA[2] = fmaf(xav[kj], w4.z, xwA[2]);
          xwA[3] = fmaf(xav[kj], w4.w, xwA[3]);
          xwB[0] = fmaf(xbv[kj], w4.x, xwB[0]);
          xwB[1] = fmaf(xbv[kj], w4.y, xwB[1]);
          xwB[2] = fmaf(xbv[kj], w4.z, xwB[2]);
          xwB[3] = fmaf(xbv[kj], w4.w, xwB[3]);
        }
      }
    }
  };

  // ---- prologue: xw(0); LIF1(0); publish m1(0) into parity-0; rendezvous ----
  if constexpr (UXW) {
    f32x4 a = __builtin_nontemporal_load((const f32x4*)(XWc + (size_t)sA * HD));
    f32x4 b = __builtin_nontemporal_load((const f32x4*)(XWc + (size_t)sB * HD));
    xwA[0] = a.x; xwA[1] = a.y; xwA[2] = a.z; xwA[3] = a.w;
    xwB[0] = b.x; xwB[1] = b.y; xwB[2] = b.z; xwB[3] = b.w;
  } else {
    compute_xw(0);
  }
  nib1A = lif_update(xwA, syn1A, mem1A, 0u);
  nib1B = lif_update(xwB, syn1B, mem1B, 0u);
  {
    u64 E0 = __ballot(nib1A & 1u), E1 = __ballot(nib1A & 2u);
    u64 E2 = __ballot(nib1A & 4u), E3 = __ballot(nib1A & 8u);
    u64 F0 = __ballot(nib1B & 1u), F1 = __ballot(nib1B & 2u);
    u64 F2 = __ballot(nib1B & 4u), F3 = __ballot(nib1B & 8u);
    if (lane < 4)
      __hip_atomic_store(&m1W[(size_t)sA * NWPS + 4 * xcd + lane],
                         pack_word(E0, E1, E2, E3, lane), __ATOMIC_RELAXED,
                         __HIP_MEMORY_SCOPE_AGENT);
    else if (lane < 8)
      __hip_atomic_store(&m1W[(size_t)sB * NWPS + 4 * xcd + (lane - 4)],
                         pack_word(F0, F1, F2, F3, lane - 4), __ATOMIC_RELAXED,
                         __HIP_MEMORY_SCOPE_AGENT);
  }
  // prefetch xw(t=1) one step early
  if constexpr (UXW) {
    xwNA = __builtin_nontemporal_load(
        (const f32x4*)(XWc + ((size_t)1 * NB + sA) * HD));
    xwNB = __builtin_nontemporal_load(
        (const f32x4*)(XWc + ((size_t)1 * NB + sB) * HD));
  }
  __syncthreads();
  if (tid == 0) {
    __hip_atomic_fetch_add(myflag, 1u, __ATOMIC_RELAXED, __HIP_MEMORY_SCOPE_AGENT);
    while (__hip_atomic_load(myflag, __ATOMIC_RELAXED,
                             __HIP_MEMORY_SCOPE_AGENT) < 8u)
      __builtin_amdgcn_s_sleep(2);
  }
  __syncthreads();

  // ---- main loop: step s gathers with m1(s); xw regs hold t=(s+1)>>1 ----
  for (int s = 0; s < NSTEPS; ++s) {
    if (s & 1) {
      if constexpr (UXW) {
        xwA[0] = xwNA.x; xwA[1] = xwNA.y; xwA[2] = xwNA.z; xwA[3] = xwNA.w;
        xwB[0] = xwNB.x; xwB[1] = xwNB.y; xwB[2] = xwNB.z; xwB[3] = xwNB.w;
      } else {
        if (s + 1 < NSTEPS) compute_xw((s + 1) >> 1);
      }
    } else {
      if constexpr (UXW) {
        int t2 = (s >> 1) + 1;
        if (t2 < 64) {
          xwNA = __builtin_nontemporal_load(
              (const f32x4*)(XWc + ((size_t)t2 * NB + sA) * HD));
          xwNB = __builtin_nontemporal_load(
              (const f32x4*)(XWc + ((size_t)t2 * NB + sB) * HD));
        }
      }
    }

    const u64* m1cur = m1W + (size_t)(s & 1) * NB * NWPS;
    u64* m1n = m1W + (size_t)((s + 1) & 1) * NB * NWPS;
    const bool last = (s == NSTEPS - 1);

    int totA, totB;
    build_ab(m1cur + (size_t)sA * NWPS, m1cur + (size_t)sB * NWPS, lstA, lstB,
             lane, totA, totB);

    float aVA[4] = {xwA[0], xwA[1], xwA[2], xwA[3]};
    float aWA[4] = {bfr[0], bfr[1], bfr[2], bfr[3]};
    float aVB[4] = {xwB[0], xwB[1], xwB[2], xwB[3]};
    float aWB[4] = {bfr[0], bfr[1], bfr[2], bfr[3]};
    gather_ab(PKb, lstA, totA, lstB, totB, aVA, aWA, aVB, aWB);

    // LIF2(s) -> m2 history; LIF1(s+1) -> next m1 buffer
    nib2A = lif_update(aWA, syn2A, mem2A, nib2A);
    nib2B = lif_update(aWB, syn2B, mem2B, nib2B);
    if (!last) {
      nib1A = lif_update(aVA, syn1A, mem1A, nib1A);
      nib1B = lif_update(aVB, syn1B, mem1B, nib1B);
    }
    {
      u64 D0 = __ballot(nib2A & 1u), D1 = __ballot(nib2A & 2u);
      u64 D2 = __ballot(nib2A & 4u), D3 = __ballot(nib2A & 8u);
      u64 G0 = __ballot(nib2B & 1u), G1 = __ballot(nib2B & 2u);
      u64 G2 = __ballot(nib2B & 4u), G3 = __ballot(nib2B & 8u);
      if (lane < 4)
        __hip_atomic_store(&m2H[((size_t)s * NB + sA) * NWPS + 4 * xcd + lane],
                           pack_word(D0, D1, D2, D3, lane), __ATOMIC_RELAXED,
                           __HIP_MEMORY_SCOPE_AGENT);
      else if (lane < 8)
        __hip_atomic_store(
            &m2H[((size_t)s * NB + sB) * NWPS + 4 * xcd + (lane - 4)],
            pack_word(G0, G1, G2, G3, lane - 4), __ATOMIC_RELAXED,
            __HIP_MEMORY_SCOPE_AGENT);
      if (!last) {
        u64 E0 = __ballot(nib1A & 1u), E1 = __ballot(nib1A & 2u);
        u64 E2 = __ballot(nib1A & 4u), E3 = __ballot(nib1A & 8u);
        u64 F0 = __ballot(nib1B & 1u), F1 = __ballot(nib1B & 2u);
        u64 F2 = __ballot(nib1B & 4u), F3 = __ballot(nib1B & 8u);
        if (lane < 4)
          __hip_atomic_store(&m1n[(size_t)sA * NWPS + 4 * xcd + lane],
                             pack_word(E0, E1, E2, E3, lane), __ATOMIC_RELAXED,
                             __HIP_MEMORY_SCOPE_AGENT);
        else if (lane < 8)
          __hip_atomic_store(&m1n[(size_t)sB * NWPS + 4 * xcd + (lane - 4)],
                             pack_word(F0, F1, F2, F3, lane - 4),
                             __ATOMIC_RELAXED, __HIP_MEMORY_SCOPE_AGENT);
      }
    }

    if (!last) {
      __syncthreads();
      if (tid == 0) {
        __hip_atomic_fetch_add(myflag, 1u, __ATOMIC_RELAXED,
                               __HIP_MEMORY_SCOPE_AGENT);
        u32 tgt = 8u * (u32)(s + 2);
        while (__hip_atomic_load(myflag, __ATOMIC_RELAXED,
                                 __HIP_MEMORY_SCOPE_AGENT) < tgt)
          __builtin_amdgcn_s_sleep(2);
      }
      __syncthreads();
    }
  }

  // ---- final rendezvous (full fence once: flush + replay-stale inv) ----
  __syncthreads();
  if (tid == 0) {
    __threadfence();
    __hip_atomic_fetch_add(done, 1u, __ATOMIC_RELEASE, __HIP_MEMORY_SCOPE_AGENT);
    while (__hip_atomic_load(done, __ATOMIC_RELAXED,
                             __HIP_MEMORY_SCOPE_AGENT) < (u32)NBLK)
      __builtin_amdgcn_s_sleep(8);
    __threadfence();
  }
  __syncthreads();

  // ---- deferred readout: 2 waves/block, wave = one sample ----
  if (wv < 2) {
    const int rsmp = blockIdx.x * 2 + wv;
    const float bor = bo[lane];
    float synr = 0.f, memr = 0.f, roprev = 0.f;
    for (int s = 0; s < NSTEPS; ++s) {
      int total = build_list_ro(m2H + ((size_t)s * NB + rsmp) * NWPS, lstA, lane);
      float a = bor;
      for (int j0 = 0; j0 < total; j0 += 8) {
        float vv[8];
#pragma unroll
        for (int u = 0; u < 8; ++u) {
          int idx = j0 + u;
          if (idx >= total) idx = j0;
          vv[u] = Wo[(((size_t)lstA[idx]) << 6) + lane];
        }
#pragma unroll
        for (int u = 0; u < 8; ++u)
          if (j0 + u < total) a += vv[u];
      }
      float nmemr = DMc * memr + SMc * synr;  // R1 shape
      float nsynr = DSc * synr + a;           // R1 shape
      memr = nmemr;
      synr = nsynr;
      if (s & 1) {
        float v = 0.5f * (roprev + nmemr);
        size_t base = ((size_t)(s >> 1) * NB + rsmp) * 32;
        if (lane < 32) out[base + lane] = v;
        else out[(size_t)64 * NB * 32 + base + (lane - 32)] = v;
      } else {
        roprev = nmemr;
      }
    }
  }
}

extern "C" void kernel_launch(void* const* d_in, const int* in_sizes, int n_in,
                              void* d_out, int out_size, void* d_ws, size_t ws_size,
                              hipStream_t stream) {
  const float* state  = (const float*)d_in[0];
  const float* target = (const float*)d_in[1];
  const float* Wi     = (const float*)d_in[2];
  const float* bi     = (const float*)d_in[3];
  const float* Vr     = (const float*)d_in[4];
  const float* Wf     = (const float*)d_in[5];
  const float* bf     = (const float*)d_in[6];
  const float* Wo     = (const float*)d_in[7];
  const float* bo     = (const float*)d_in[8];
  float* out = (float*)d_out;
  char* wsb = (char*)d_ws;

  const int use_xw = (ws_size >= OFF_XW + SZ_XW) ? 1 : 0;

  init_ws<<<128, 256, 0, stream>>>((u64*)(wsb + OFF_M1W), (u32*)(wsb + OFF_FLAG),
                                   (u32*)(wsb + OFF_CNT), (u32*)(wsb + OFF_DONE));
  pack_kernel<<<HD, 256, 0, stream>>>(Vr, Wf, (float*)(wsb + OFF_PK));
  if (use_xw)
    xw_kernel<<<dim3(8, 2048), 256, 0, stream>>>(state, target, Wi, bi,
                                                 (float*)(wsb + OFF_XW));

  void* args[] = {(void*)&state, (void*)&target, (void*)&Wi, (void*)&bi,
                  (void*)&Vr, (void*)&Wf, (void*)&bf, (void*)&Wo, (void*)&bo,
                  (void*)&out, (void*)&wsb};
  if (use_xw)
    (void)hipLaunchCooperativeKernel(rsnn_coop<1>, dim3(NBLK), dim3(THREADS),
                                     args, 0, stream);
  else
    (void)hipLaunchCooperativeKernel(rsnn_coop<0>, dim3(NBLK), dim3(THREADS),
                                     args, 0, stream);
}

// Round 19
// 3411.900 us; speedup vs baseline: 3.1411x; 1.0112x over previous
//
#include <hip/hip_runtime.h>
#include <stdint.h>

// PolicyNetRSNNPB R19 = R18 (best: 3450us) + PARALLEL READOUT TAIL.
// R18's tail: 2/8 waves per block, 128 serial steps of {MALL mask load +
// Wo gather} ~ 250-400us at 25% utilization. Ir = bo + ns2@Wo has NO
// recurrence -> phase 1: all 8 waves compute the block's 256 (smp,step) Ir
// vectors in parallel (same ascending-k order -> bit-exact), stored in the
// DEAD PK region (PK unused post-loop; rewritten by pack_kernel per replay).
// Phase 2: 2 waves run the cheap 128-step leaky-integrator scan on
// block-local Ir rows (L2 hits). Main loop unchanged from R18.
// absmax 0.0 preserved through R18.

typedef unsigned long long u64;
typedef unsigned int u32;
typedef float f32x4 __attribute__((ext_vector_type(4)));

#define NB 512
#define HD 2048
#define NSTEPS 128
#define THREADS 512
#define NBLK 256
#define COLS 256
#define SPB 16
#define NWPS 32
#define LSTN 832

#define DMc 0.8187307530779818f
#define DSc 0.6065306597126334f
#define SMc 0.18126924692201818f

// ---- ws layout ----
#define OFF_M1W 0
#define SZ_M1W ((size_t)2 * NB * NWPS * 8)       // 256 KB
#define OFF_M2H (OFF_M1W + SZ_M1W)
#define SZ_M2H ((size_t)NSTEPS * NB * NWPS * 8)  // 16 MB
#define OFF_FLAG (OFF_M2H + SZ_M2H)
#define SZ_FLAG (32 * 32 * 4)
#define OFF_CNT (OFF_FLAG + SZ_FLAG)
#define OFF_DONE (OFF_CNT + 64)
#define OFF_PK (((size_t)(OFF_DONE + 4) + 4194303) & ~(size_t)4194303)
#define SZ_PK ((size_t)8 * HD * 512 * 4)         // 32 MB (exactly 4.0MB/XCD)
#define OFF_XW (((OFF_PK + SZ_PK) + 255) & ~(size_t)255)
#define SZ_XW ((size_t)64 * NB * HD * 4)         // 256 MB
// RO (phase-1 Ir buffer, 16MB) ALIASES the dead PK region post-main-loop:
// per block: 2 samples x 128 steps x 64 cols x 4B = 64KB.
#define OFF_RO OFF_PK

#define HWREG_XCC_ID (20 | ((4 - 1) << 11))

__global__ void init_ws(u64* __restrict__ m1W, u32* __restrict__ flags,
                        u32* __restrict__ cnt, u32* __restrict__ done) {
  int i = blockIdx.x * 256 + threadIdx.x;
  if (i < 2 * NB * NWPS) m1W[i] = 0ULL;
  if (i < 32 * 32) flags[i] = 0u;
  if (i < 8) cnt[i] = 0u;
  if (i == 0) *done = 0u;
}

// PK[xcd][k][0..255]=Vr[k][xcd*256+..], [256..511]=Wf[k][..]
__global__ __launch_bounds__(256) void pack_kernel(
    const float* __restrict__ Vr, const float* __restrict__ Wf,
    float* __restrict__ PK) {
  const int k = blockIdx.x;
  const int tid = threadIdx.x;
  for (int c = tid; c < HD; c += 256) {
    int xcd = c >> 8, cc = c & 255;
    size_t base = ((size_t)xcd * HD + k) * 512;
    __builtin_nontemporal_store(Vr[(size_t)k * HD + c], &PK[base + cc]);
    __builtin_nontemporal_store(Wf[(size_t)k * HD + c], &PK[base + 256 + cc]);
  }
}

// XW[t*NB+n][h] = bi[h] + x(t,n,:) @ Wi
__global__ __launch_bounds__(256) void xw_kernel(
    const float* __restrict__ state, const float* __restrict__ target,
    const float* __restrict__ Wi, const float* __restrict__ bi,
    float* __restrict__ XW) {
  __shared__ float xl[16][128];
  const int tid = threadIdx.x;
  const int col = blockIdx.x * 256 + tid;
  const int r0 = blockIdx.y * 16;

  for (int idx = tid; idx < 16 * 128; idx += 256) {
    int r = idx >> 7, k = idx & 127;
    int gg = r0 + r;
    int t = gg >> 9, n = gg & 511;
    float v = (k < 64) ? state[((size_t)(t * NB + n)) * 64 + k]
                       : target[((size_t)(t * NB + n)) * 64 + (k - 64)];
    xl[r][k] = v;
  }
  __syncthreads();

  float acc[16];
  float b = bi[col];
#pragma unroll
  for (int r = 0; r < 16; ++r) acc[r] = b;
  for (int k = 0; k < 128; ++k) {
    float w = Wi[(size_t)k * HD + col];
#pragma unroll
    for (int r = 0; r < 16; ++r) acc[r] = fmaf(xl[r][k], w, acc[r]);
  }
#pragma unroll
  for (int r = 0; r < 16; ++r)
    __builtin_nontemporal_store(acc[r], &XW[(size_t)(r0 + r) * HD + col]);
}

// bit i of low-16 -> bit 4i
__device__ __forceinline__ u64 spread4(u64 x) {
  x &= 0xffffULL;
  x = (x | (x << 24)) & 0x000000FF000000FFULL;
  x = (x | (x << 12)) & 0x000F000F000F000FULL;
  x = (x | (x << 6))  & 0x0303030303030303ULL;
  x = (x | (x << 3))  & 0x1111111111111111ULL;
  return x;
}

__device__ __forceinline__ u64 pack_word(u64 B0, u64 B1, u64 B2, u64 B3, int q) {
  int sh = q * 16;
  return spread4(B0 >> sh) | (spread4(B1 >> sh) << 1) |
         (spread4(B2 >> sh) << 2) | (spread4(B3 >> sh) << 3);
}

// merged A+B list build (one atomic round, half-wave scans)
__device__ __forceinline__ void build_ab(const u64* __restrict__ mA,
                                         const u64* __restrict__ mB,
                                         uint16_t* __restrict__ lstA,
                                         uint16_t* __restrict__ lstB,
                                         int lane, int& totA, int& totB) {
  const int hf = lane >> 5, wl = lane & 31;
  const u64* src = hf ? mB : mA;
  u64 w = __hip_atomic_load(src + wl, __ATOMIC_RELAXED,
                            __HIP_MEMORY_SCOPE_AGENT);
  int pc = __popcll(w);
  int pre = pc;
#pragma unroll
  for (int off = 1; off < 32; off <<= 1) {
    int v = __shfl_up(pre, off, 32);
    if (wl >= off) pre += v;
  }
  int excl = pre - pc;
  totA = __shfl(pre, 31);
  totB = __shfl(pre, 63);
  uint16_t* lw = hf ? lstB : lstA;
  int kb = wl << 6;
  while (w) {
    int b = __builtin_ctzll(w);
    w &= w - 1;
    if (excl < LSTN) lw[excl] = (uint16_t)(kb + b);
    ++excl;
  }
  asm volatile("s_waitcnt lgkmcnt(0)" ::: "memory");
  totA = totA < LSTN ? totA : LSTN;
  totB = totB < LSTN ? totB : LSTN;
}

// full-wave list build (readout; plain loads)
__device__ __forceinline__ int build_list_ro(const u64* __restrict__ mwords,
                                             uint16_t* __restrict__ lstw,
                                             int lane) {
  u64 w = (lane < NWPS) ? mwords[lane] : 0ULL;
  int pc = __popcll(w);
  int pre = pc;
#pragma unroll
  for (int off = 1; off < 64; off <<= 1) {
    int v = __shfl_up(pre, off);
    if (lane >= off) pre += v;
  }
  int excl = pre - pc;
  int total = __shfl(pre, 63);
  int kb = lane << 6;
  while (w) {
    int b = __builtin_ctzll(w);
    w &= w - 1;
    if (excl < LSTN) lstw[excl] = (uint16_t)(kb + b);
    ++excl;
  }
  asm volatile("s_waitcnt lgkmcnt(0)" ::: "memory");
  return total < LSTN ? total : LSTN;
}

__device__ __forceinline__ u32 lif_update(const float acc[4], float syn[4],
                                          float mem[4], u32 snib) {
  u32 nib = 0;
#pragma unroll
  for (int j = 0; j < 4; ++j) {
    float so = (float)((snib >> j) & 1u);
    float nmem = (DMc * mem[j] + SMc * syn[j]) * (1.0f - so);  // R1 shape
    float nsyn = DSc * syn[j] + acc[j];                         // R1 shape
    mem[j] = nmem;
    syn[j] = nsyn;
    if ((nmem - 1.0f) > 0.0f) nib |= (1u << j);
  }
  return nib;
}

// A+B interleaved dual gather: full batches of BOTH samples unguarded;
// guarded tail. Ascending k per sample, separate accumulators -> bit-exact.
__device__ __forceinline__ void gather_ab(const float* __restrict__ PKb,
                                          const uint16_t* __restrict__ lstA,
                                          int totA,
                                          const uint16_t* __restrict__ lstB,
                                          int totB, float aVA[4], float aWA[4],
                                          float aVB[4], float aWB[4]) {
  const int mn = totA < totB ? totA : totB;
  const int mx = totA > totB ? totA : totB;
  const int fullBoth = mn & ~7;

  int j0 = 0;
  for (; j0 < fullBoth; j0 += 8) {
    f32x4 va[8], wa[8], vb[8], wb[8];
#pragma unroll
    for (int u = 0; u < 8; ++u) {
      size_t offA = ((size_t)lstA[j0 + u]) << 9;
      va[u] = *(const f32x4*)(PKb + offA);
      wa[u] = *(const f32x4*)(PKb + offA + 256);
    }
#pragma unroll
    for (int u = 0; u < 8; ++u) {
      size_t offB = ((size_t)lstB[j0 + u]) << 9;
      vb[u] = *(const f32x4*)(PKb + offB);
      wb[u] = *(const f32x4*)(PKb + offB + 256);
    }
#pragma unroll
    for (int u = 0; u < 8; ++u) {
      aVA[0] += va[u].x; aVA[1] += va[u].y; aVA[2] += va[u].z; aVA[3] += va[u].w;
      aWA[0] += wa[u].x; aWA[1] += wa[u].y; aWA[2] += wa[u].z; aWA[3] += wa[u].w;
    }
#pragma unroll
    for (int u = 0; u < 8; ++u) {
      aVB[0] += vb[u].x; aVB[1] += vb[u].y; aVB[2] += vb[u].z; aVB[3] += vb[u].w;
      aWB[0] += wb[u].x; aWB[1] += wb[u].y; aWB[2] += wb[u].z; aWB[3] += wb[u].w;
    }
  }
  for (; j0 < mx; j0 += 8) {
    f32x4 va[8], wa[8], vb[8], wb[8];
#pragma unroll
    for (int u = 0; u < 8; ++u) {
      int ia = j0 + u;
      if (ia >= totA) ia = 0;
      size_t offA = ((size_t)lstA[ia]) << 9;
      va[u] = *(const f32x4*)(PKb + offA);
      wa[u] = *(const f32x4*)(PKb + offA + 256);
    }
#pragma unroll
    for (int u = 0; u < 8; ++u) {
      int ib = j0 + u;
      if (ib >= totB) ib = 0;
      size_t offB = ((size_t)lstB[ib]) << 9;
      vb[u] = *(const f32x4*)(PKb + offB);
      wb[u] = *(const f32x4*)(PKb + offB + 256);
    }
#pragma unroll
    for (int u = 0; u < 8; ++u)
      if (j0 + u < totA) {
        aVA[0] += va[u].x; aVA[1] += va[u].y; aVA[2] += va[u].z; aVA[3] += va[u].w;
        aWA[0] += wa[u].x; aWA[1] += wa[u].y; aWA[2] += wa[u].z; aWA[3] += wa[u].w;
      }
#pragma unroll
    for (int u = 0; u < 8; ++u)
      if (j0 + u < totB) {
        aVB[0] += vb[u].x; aVB[1] += vb[u].y; aVB[2] += vb[u].z; aVB[3] += vb[u].w;
        aWB[0] += wb[u].x; aWB[1] += wb[u].y; aWB[2] += wb[u].z; aWB[3] += wb[u].w;
      }
  }
}

template <int UXW>
__global__ __launch_bounds__(THREADS, 2) void rsnn_coop(
    const float* __restrict__ state, const float* __restrict__ target,
    const float* __restrict__ Wi, const float* __restrict__ bi,
    const float* __restrict__ Vr, const float* __restrict__ Wf,
    const float* __restrict__ bf, const float* __restrict__ Wo,
    const float* __restrict__ bo, float* __restrict__ out,
    char* __restrict__ wsb) {
  __shared__ float Wi_s[128 * COLS];      // 128 KB (fallback xw; pins 1 blk/CU)
  __shared__ uint16_t lstA_s[8][LSTN];    // 13 KB
  __shared__ uint16_t lstB_s[8][LSTN];    // 13 KB
  __shared__ int sh_xcd, sh_rank;

  u64* m1W = (u64*)(wsb + OFF_M1W);
  u64* m2H = (u64*)(wsb + OFF_M2H);
  u32* flags = (u32*)(wsb + OFF_FLAG);
  u32* cnt = (u32*)(wsb + OFF_CNT);
  u32* done = (u32*)(wsb + OFF_DONE);
  const float* PK = (const float*)(wsb + OFF_PK);
  const float* XW = (const float*)(wsb + OFF_XW);
  float* RO = (float*)(wsb + OFF_RO);   // aliases PK; used only post-loop

  const int tid = threadIdx.x;
  const int wv = tid >> 6;      // wave = 2 samples
  const int lane = tid & 63;    // lane = 4 columns

  if (tid == 0) {
    int x = __builtin_amdgcn_s_getreg(HWREG_XCC_ID) & 7;
    sh_xcd = x;
    sh_rank = atomicAdd(&cnt[x], 1u) & 31;
  }
  __syncthreads();
  const int xcd = sh_xcd;
  const int g = sh_rank;
  const int c0 = xcd * COLS;
  const int sA = g * SPB + wv * 2, sB = sA + 1;

  if constexpr (!UXW) {
    for (int i = tid; i < 128 * COLS; i += THREADS) {
      int k = i >> 8, c = i & 255;
      Wi_s[i] = Wi[(size_t)k * HD + c0 + c];
    }
  }
  uint16_t* lstA = &lstA_s[wv][0];
  uint16_t* lstB = &lstB_s[wv][0];
  if (lane == 0) { lstA[0] = 0; lstB[0] = 0; }   // guard rows for clamped loads

  float bir[4], bfr[4];
#pragma unroll
  for (int j = 0; j < 4; ++j) {
    bir[j] = bi[c0 + lane * 4 + j];
    bfr[j] = bf[c0 + lane * 4 + j];
  }

  float syn1A[4], mem1A[4], syn2A[4], mem2A[4];
  float syn1B[4], mem1B[4], syn2B[4], mem2B[4];
#pragma unroll
  for (int j = 0; j < 4; ++j) {
    syn1A[j] = 0.f; mem1A[j] = 0.f; syn2A[j] = 0.f; mem2A[j] = 0.f;
    syn1B[j] = 0.f; mem1B[j] = 0.f; syn2B[j] = 0.f; mem2B[j] = 0.f;
  }
  u32 nib1A = 0u, nib1B = 0u, nib2A = 0u, nib2B = 0u;
  float xwA[4], xwB[4];
  f32x4 xwNA, xwNB;

  const float* PKb = PK + (size_t)xcd * HD * 512 + lane * 4;
  const float* XWc = XW + c0 + lane * 4;
  u32* myflag = &flags[g * 32];

  __syncthreads();  // Wi_s / lst guards ready

  // xw(t) for A,B from Wi_s (k-ascending fmaf; fallback only)
  auto compute_xw = [&](int t2) {
#pragma unroll
    for (int j = 0; j < 4; ++j) { xwA[j] = bir[j]; xwB[j] = bir[j]; }
#pragma unroll
    for (int half = 0; half < 2; ++half) {
      const float* pA = (half ? target : state) + ((size_t)t2 * NB + sA) * 64;
      const float* pB = (half ? target : state) + ((size_t)t2 * NB + sB) * 64;
      for (int q = 0; q < 16; ++q) {
        f32x4 xa = *(const f32x4*)(pA + 4 * q);
        f32x4 xb = *(const f32x4*)(pB + 4 * q);
        float xav[4] = {xa.x, xa.y, xa.z, xa.w};
        float xbv[4] = {xb.x, xb.y, xb.z, xb.w};
#pragma unroll
        for (int kj = 0; kj < 4; ++kj) {
          const f32x4 w4 =
              *(const f32x4*)&Wi_s[(half * 64 + 4 * q + kj) * COLS + lane * 4];
          xwA[0] = fmaf(xav[kj], w4.x, xwA[0]);
          xwA[1] = fmaf(xav[kj], w4.y, xwA[1]);
          xwA[2] = fmaf(xav[kj], w4.z, xwA[2]);
          xwA[3] = fmaf(xav[kj], w4.w, xwA[3]);
          xwB[0] = fmaf(xbv[kj], w4.x, xwB[0]);
          xwB[1] = fmaf(xbv[kj], w4.y, xwB[1]);
          xwB[2] = fmaf(xbv[kj], w4.z, xwB[2]);
          xwB[3] = fmaf(xbv[kj], w4.w, xwB[3]);
        }
      }
    }
  };

  // ---- prologue: xw(0); LIF1(0); publish m1(0) into parity-0; rendezvous ----
  if constexpr (UXW) {
    f32x4 a = __builtin_nontemporal_load((const f32x4*)(XWc + (size_t)sA * HD));
    f32x4 b = __builtin_nontemporal_load((const f32x4*)(XWc + (size_t)sB * HD));
    xwA[0] = a.x; xwA[1] = a.y; xwA[2] = a.z; xwA[3] = a.w;
    xwB[0] = b.x; xwB[1] = b.y; xwB[2] = b.z; xwB[3] = b.w;
  } else {
    compute_xw(0);
  }
  nib1A = lif_update(xwA, syn1A, mem1A, 0u);
  nib1B = lif_update(xwB, syn1B, mem1B, 0u);
  {
    u64 E0 = __ballot(nib1A & 1u), E1 = __ballot(nib1A & 2u);
    u64 E2 = __ballot(nib1A & 4u), E3 = __ballot(nib1A & 8u);
    u64 F0 = __ballot(nib1B & 1u), F1 = __ballot(nib1B & 2u);
    u64 F2 = __ballot(nib1B & 4u), F3 = __ballot(nib1B & 8u);
    if (lane < 4)
      __hip_atomic_store(&m1W[(size_t)sA * NWPS + 4 * xcd + lane],
                         pack_word(E0, E1, E2, E3, lane), __ATOMIC_RELAXED,
                         __HIP_MEMORY_SCOPE_AGENT);
    else if (lane < 8)
      __hip_atomic_store(&m1W[(size_t)sB * NWPS + 4 * xcd + (lane - 4)],
                         pack_word(F0, F1, F2, F3, lane - 4), __ATOMIC_RELAXED,
                         __HIP_MEMORY_SCOPE_AGENT);
  }
  if constexpr (UXW) {
    xwNA = __builtin_nontemporal_load(
        (const f32x4*)(XWc + ((size_t)1 * NB + sA) * HD));
    xwNB = __builtin_nontemporal_load(
        (const f32x4*)(XWc + ((size_t)1 * NB + sB) * HD));
  }
  __syncthreads();
  if (tid == 0) {
    __hip_atomic_fetch_add(myflag, 1u, __ATOMIC_RELAXED, __HIP_MEMORY_SCOPE_AGENT);
    while (__hip_atomic_load(myflag, __ATOMIC_RELAXED,
                             __HIP_MEMORY_SCOPE_AGENT) < 8u)
      __builtin_amdgcn_s_sleep(2);
  }
  __syncthreads();

  // ---- main loop: step s gathers with m1(s); xw regs hold t=(s+1)>>1 ----
  for (int s = 0; s < NSTEPS; ++s) {
    if (s & 1) {
      if constexpr (UXW) {
        xwA[0] = xwNA.x; xwA[1] = xwNA.y; xwA[2] = xwNA.z; xwA[3] = xwNA.w;
        xwB[0] = xwNB.x; xwB[1] = xwNB.y; xwB[2] = xwNB.z; xwB[3] = xwNB.w;
      } else {
        if (s + 1 < NSTEPS) compute_xw((s + 1) >> 1);
      }
    } else {
      if constexpr (UXW) {
        int t2 = (s >> 1) + 1;
        if (t2 < 64) {
          xwNA = __builtin_nontemporal_load(
              (const f32x4*)(XWc + ((size_t)t2 * NB + sA) * HD));
          xwNB = __builtin_nontemporal_load(
              (const f32x4*)(XWc + ((size_t)t2 * NB + sB) * HD));
        }
      }
    }

    const u64* m1cur = m1W + (size_t)(s & 1) * NB * NWPS;
    u64* m1n = m1W + (size_t)((s + 1) & 1) * NB * NWPS;
    const bool last = (s == NSTEPS - 1);

    int totA, totB;
    build_ab(m1cur + (size_t)sA * NWPS, m1cur + (size_t)sB * NWPS, lstA, lstB,
             lane, totA, totB);

    float aVA[4] = {xwA[0], xwA[1], xwA[2], xwA[3]};
    float aWA[4] = {bfr[0], bfr[1], bfr[2], bfr[3]};
    float aVB[4] = {xwB[0], xwB[1], xwB[2], xwB[3]};
    float aWB[4] = {bfr[0], bfr[1], bfr[2], bfr[3]};
    gather_ab(PKb, lstA, totA, lstB, totB, aVA, aWA, aVB, aWB);

    // LIF2(s) -> m2 history; LIF1(s+1) -> next m1 buffer
    nib2A = lif_update(aWA, syn2A, mem2A, nib2A);
    nib2B = lif_update(aWB, syn2B, mem2B, nib2B);
    if (!last) {
      nib1A = lif_update(aVA, syn1A, mem1A, nib1A);
      nib1B = lif_update(aVB, syn1B, mem1B, nib1B);
    }
    {
      u64 D0 = __ballot(nib2A & 1u), D1 = __ballot(nib2A & 2u);
      u64 D2 = __ballot(nib2A & 4u), D3 = __ballot(nib2A & 8u);
      u64 G0 = __ballot(nib2B & 1u), G1 = __ballot(nib2B & 2u);
      u64 G2 = __ballot(nib2B & 4u), G3 = __ballot(nib2B & 8u);
      if (lane < 4)
        __hip_atomic_store(&m2H[((size_t)s * NB + sA) * NWPS + 4 * xcd + lane],
                           pack_word(D0, D1, D2, D3, lane), __ATOMIC_RELAXED,
                           __HIP_MEMORY_SCOPE_AGENT);
      else if (lane < 8)
        __hip_atomic_store(
            &m2H[((size_t)s * NB + sB) * NWPS + 4 * xcd + (lane - 4)],
            pack_word(G0, G1, G2, G3, lane - 4), __ATOMIC_RELAXED,
            __HIP_MEMORY_SCOPE_AGENT);
      if (!last) {
        u64 E0 = __ballot(nib1A & 1u), E1 = __ballot(nib1A & 2u);
        u64 E2 = __ballot(nib1A & 4u), E3 = __ballot(nib1A & 8u);
        u64 F0 = __ballot(nib1B & 1u), F1 = __ballot(nib1B & 2u);
        u64 F2 = __ballot(nib1B & 4u), F3 = __ballot(nib1B & 8u);
        if (lane < 4)
          __hip_atomic_store(&m1n[(size_t)sA * NWPS + 4 * xcd + lane],
                             pack_word(E0, E1, E2, E3, lane), __ATOMIC_RELAXED,
                             __HIP_MEMORY_SCOPE_AGENT);
        else if (lane < 8)
          __hip_atomic_store(&m1n[(size_t)sB * NWPS + 4 * xcd + (lane - 4)],
                             pack_word(F0, F1, F2, F3, lane - 4),
                             __ATOMIC_RELAXED, __HIP_MEMORY_SCOPE_AGENT);
      }
    }

    if (!last) {
      __syncthreads();
      if (tid == 0) {
        __hip_atomic_fetch_add(myflag, 1u, __ATOMIC_RELAXED,
                               __HIP_MEMORY_SCOPE_AGENT);
        u32 tgt = 8u * (u32)(s + 2);
        while (__hip_atomic_load(myflag, __ATOMIC_RELAXED,
                                 __HIP_MEMORY_SCOPE_AGENT) < tgt)
          __builtin_amdgcn_s_sleep(2);
      }
      __syncthreads();
    }
  }

  // ---- final rendezvous (full fence once: flush + replay-stale inv) ----
  __syncthreads();
  if (tid == 0) {
    __threadfence();
    __hip_atomic_fetch_add(done, 1u, __ATOMIC_RELEASE, __HIP_MEMORY_SCOPE_AGENT);
    while (__hip_atomic_load(done, __ATOMIC_RELAXED,
                             __HIP_MEMORY_SCOPE_AGENT) < (u32)NBLK)
      __builtin_amdgcn_s_sleep(8);
    __threadfence();
  }
  __syncthreads();

  // ==== PARALLEL READOUT ====
  // phase 1: all 8 waves compute Ir for this block's 2 samples x 128 steps.
  // job j = wv + 8*i (i<32): loc = j>>7, s = j&127. Same ascending-k order.
  {
    const float bor = bo[lane];
    float* ROb = RO + (size_t)blockIdx.x * 2 * NSTEPS * 64;
    for (int i = 0; i < 32; ++i) {
      int j = wv + 8 * i;
      int loc = j >> 7, s = j & 127;
      int smp = blockIdx.x * 2 + loc;
      int total = build_list_ro(m2H + ((size_t)s * NB + smp) * NWPS, lstA, lane);
      float a = bor;
      for (int j0 = 0; j0 < total; j0 += 8) {
        float vv[8];
#pragma unroll
        for (int u = 0; u < 8; ++u) {
          int idx = j0 + u;
          if (idx >= total) idx = j0;
          vv[u] = Wo[(((size_t)lstA[idx]) << 6) + lane];
        }
#pragma unroll
        for (int u = 0; u < 8; ++u)
          if (j0 + u < total) a += vv[u];
      }
      ROb[(size_t)(loc * NSTEPS + s) * 64 + lane] = a;
    }
  }
  __syncthreads();   // Ir complete (block-local)

  // phase 2: 2 waves run the cheap leaky-integrator scan (identical math).
  if (wv < 2) {
    const int rsmp = blockIdx.x * 2 + wv;
    const float* ROb = RO + ((size_t)blockIdx.x * 2 + wv) * NSTEPS * 64;
    float synr = 0.f, memr = 0.f, roprev = 0.f;
    for (int s = 0; s < NSTEPS; ++s) {
      float a = ROb[(size_t)s * 64 + lane];
      float nmemr = DMc * memr + SMc * synr;  // R1 shape
      float nsynr = DSc * synr + a;           // R1 shape
      memr = nmemr;
      synr = nsynr;
      if (s & 1) {
        float v = 0.5f * (roprev + nmemr);
        size_t base = ((size_t)(s >> 1) * NB + rsmp) * 32;
        if (lane < 32) out[base + lane] = v;
        else out[(size_t)64 * NB * 32 + base + (lane - 32)] = v;
      } else {
        roprev = nmemr;
      }
    }
  }
}

extern "C" void kernel_launch(void* const* d_in, const int* in_sizes, int n_in,
                              void* d_out, int out_size, void* d_ws, size_t ws_size,
                              hipStream_t stream) {
  const float* state  = (const float*)d_in[0];
  const float* target = (const float*)d_in[1];
  const float* Wi     = (const float*)d_in[2];
  const float* bi     = (const float*)d_in[3];
  const float* Vr     = (const float*)d_in[4];
  const float* Wf     = (const float*)d_in[5];
  const float* bf     = (const float*)d_in[6];
  const float* Wo     = (const float*)d_in[7];
  const float* bo     = (const float*)d_in[8];
  float* out = (float*)d_out;
  char* wsb = (char*)d_ws;

  const int use_xw = (ws_size >= OFF_XW + SZ_XW) ? 1 : 0;

  init_ws<<<128, 256, 0, stream>>>((u64*)(wsb + OFF_M1W), (u32*)(wsb + OFF_FLAG),
                                   (u32*)(wsb + OFF_CNT), (u32*)(wsb + OFF_DONE));
  pack_kernel<<<HD, 256, 0, stream>>>(Vr, Wf, (float*)(wsb + OFF_PK));
  if (use_xw)
    xw_kernel<<<dim3(8, 2048), 256, 0, stream>>>(state, target, Wi, bi,
                                                 (float*)(wsb + OFF_XW));

  void* args[] = {(void*)&state, (void*)&target, (void*)&Wi, (void*)&bi,
                  (void*)&Vr, (void*)&Wf, (void*)&bf, (void*)&Wo, (void*)&bo,
                  (void*)&out, (void*)&wsb};
  if (use_xw)
    (void)hipLaunchCooperativeKernel(rsnn_coop<1>, dim3(NBLK), dim3(THREADS),
                                     args, 0, stream);
  else
    (void)hipLaunchCooperativeKernel(rsnn_coop<0>, dim3(NBLK), dim3(THREADS),
                                     args, 0, stream);
}

// Round 20
// 3322.279 us; speedup vs baseline: 3.2258x; 1.0270x over previous
//
#include <hip/hip_runtime.h>
#include <stdint.h>

// PolicyNetRSNNPB R20 = R19 (best: 3412us) + SPLIT-PHASE ARRIVE.
// R19 step order: gather -> LIF2 -> LIF1 -> all stores -> barrier -> arrive.
// Only m1(s+1) is consumed by siblings next step; m2H(s) is consumed after
// the FINAL fence. R20 moves LIF2 + m2H stores + xw prefetch into the poll
// shadow: LIF1+m1n -> barrier -> arrive -> [shadow] -> barrier -> poll.
// Shaves the group-wide step cadence by the shadow cost. Everything else
// verbatim R19. Bit-exact order preserved (absmax 0.0 through R19).

typedef unsigned long long u64;
typedef unsigned int u32;
typedef float f32x4 __attribute__((ext_vector_type(4)));

#define NB 512
#define HD 2048
#define NSTEPS 128
#define THREADS 512
#define NBLK 256
#define COLS 256
#define SPB 16
#define NWPS 32
#define LSTN 832

#define DMc 0.8187307530779818f
#define DSc 0.6065306597126334f
#define SMc 0.18126924692201818f

// ---- ws layout ----
#define OFF_M1W 0
#define SZ_M1W ((size_t)2 * NB * NWPS * 8)       // 256 KB
#define OFF_M2H (OFF_M1W + SZ_M1W)
#define SZ_M2H ((size_t)NSTEPS * NB * NWPS * 8)  // 16 MB
#define OFF_FLAG (OFF_M2H + SZ_M2H)
#define SZ_FLAG (32 * 32 * 4)
#define OFF_CNT (OFF_FLAG + SZ_FLAG)
#define OFF_DONE (OFF_CNT + 64)
#define OFF_PK (((size_t)(OFF_DONE + 4) + 4194303) & ~(size_t)4194303)
#define SZ_PK ((size_t)8 * HD * 512 * 4)         // 32 MB (exactly 4.0MB/XCD)
#define OFF_XW (((OFF_PK + SZ_PK) + 255) & ~(size_t)255)
#define SZ_XW ((size_t)64 * NB * HD * 4)         // 256 MB
#define OFF_RO OFF_PK   // phase-1 Ir buffer aliases dead PK post-main-loop

#define HWREG_XCC_ID (20 | ((4 - 1) << 11))

__global__ void init_ws(u64* __restrict__ m1W, u32* __restrict__ flags,
                        u32* __restrict__ cnt, u32* __restrict__ done) {
  int i = blockIdx.x * 256 + threadIdx.x;
  if (i < 2 * NB * NWPS) m1W[i] = 0ULL;
  if (i < 32 * 32) flags[i] = 0u;
  if (i < 8) cnt[i] = 0u;
  if (i == 0) *done = 0u;
}

// PK[xcd][k][0..255]=Vr[k][xcd*256+..], [256..511]=Wf[k][..]
__global__ __launch_bounds__(256) void pack_kernel(
    const float* __restrict__ Vr, const float* __restrict__ Wf,
    float* __restrict__ PK) {
  const int k = blockIdx.x;
  const int tid = threadIdx.x;
  for (int c = tid; c < HD; c += 256) {
    int xcd = c >> 8, cc = c & 255;
    size_t base = ((size_t)xcd * HD + k) * 512;
    __builtin_nontemporal_store(Vr[(size_t)k * HD + c], &PK[base + cc]);
    __builtin_nontemporal_store(Wf[(size_t)k * HD + c], &PK[base + 256 + cc]);
  }
}

// XW[t*NB+n][h] = bi[h] + x(t,n,:) @ Wi
__global__ __launch_bounds__(256) void xw_kernel(
    const float* __restrict__ state, const float* __restrict__ target,
    const float* __restrict__ Wi, const float* __restrict__ bi,
    float* __restrict__ XW) {
  __shared__ float xl[16][128];
  const int tid = threadIdx.x;
  const int col = blockIdx.x * 256 + tid;
  const int r0 = blockIdx.y * 16;

  for (int idx = tid; idx < 16 * 128; idx += 256) {
    int r = idx >> 7, k = idx & 127;
    int gg = r0 + r;
    int t = gg >> 9, n = gg & 511;
    float v = (k < 64) ? state[((size_t)(t * NB + n)) * 64 + k]
                       : target[((size_t)(t * NB + n)) * 64 + (k - 64)];
    xl[r][k] = v;
  }
  __syncthreads();

  float acc[16];
  float b = bi[col];
#pragma unroll
  for (int r = 0; r < 16; ++r) acc[r] = b;
  for (int k = 0; k < 128; ++k) {
    float w = Wi[(size_t)k * HD + col];
#pragma unroll
    for (int r = 0; r < 16; ++r) acc[r] = fmaf(xl[r][k], w, acc[r]);
  }
#pragma unroll
  for (int r = 0; r < 16; ++r)
    __builtin_nontemporal_store(acc[r], &XW[(size_t)(r0 + r) * HD + col]);
}

// bit i of low-16 -> bit 4i
__device__ __forceinline__ u64 spread4(u64 x) {
  x &= 0xffffULL;
  x = (x | (x << 24)) & 0x000000FF000000FFULL;
  x = (x | (x << 12)) & 0x000F000F000F000FULL;
  x = (x | (x << 6))  & 0x0303030303030303ULL;
  x = (x | (x << 3))  & 0x1111111111111111ULL;
  return x;
}

__device__ __forceinline__ u64 pack_word(u64 B0, u64 B1, u64 B2, u64 B3, int q) {
  int sh = q * 16;
  return spread4(B0 >> sh) | (spread4(B1 >> sh) << 1) |
         (spread4(B2 >> sh) << 2) | (spread4(B3 >> sh) << 3);
}

// merged A+B list build (one atomic round, half-wave scans)
__device__ __forceinline__ void build_ab(const u64* __restrict__ mA,
                                         const u64* __restrict__ mB,
                                         uint16_t* __restrict__ lstA,
                                         uint16_t* __restrict__ lstB,
                                         int lane, int& totA, int& totB) {
  const int hf = lane >> 5, wl = lane & 31;
  const u64* src = hf ? mB : mA;
  u64 w = __hip_atomic_load(src + wl, __ATOMIC_RELAXED,
                            __HIP_MEMORY_SCOPE_AGENT);
  int pc = __popcll(w);
  int pre = pc;
#pragma unroll
  for (int off = 1; off < 32; off <<= 1) {
    int v = __shfl_up(pre, off, 32);
    if (wl >= off) pre += v;
  }
  int excl = pre - pc;
  totA = __shfl(pre, 31);
  totB = __shfl(pre, 63);
  uint16_t* lw = hf ? lstB : lstA;
  int kb = wl << 6;
  while (w) {
    int b = __builtin_ctzll(w);
    w &= w - 1;
    if (excl < LSTN) lw[excl] = (uint16_t)(kb + b);
    ++excl;
  }
  asm volatile("s_waitcnt lgkmcnt(0)" ::: "memory");
  totA = totA < LSTN ? totA : LSTN;
  totB = totB < LSTN ? totB : LSTN;
}

// full-wave list build (readout; plain loads)
__device__ __forceinline__ int build_list_ro(const u64* __restrict__ mwords,
                                             uint16_t* __restrict__ lstw,
                                             int lane) {
  u64 w = (lane < NWPS) ? mwords[lane] : 0ULL;
  int pc = __popcll(w);
  int pre = pc;
#pragma unroll
  for (int off = 1; off < 64; off <<= 1) {
    int v = __shfl_up(pre, off);
    if (lane >= off) pre += v;
  }
  int excl = pre - pc;
  int total = __shfl(pre, 63);
  int kb = lane << 6;
  while (w) {
    int b = __builtin_ctzll(w);
    w &= w - 1;
    if (excl < LSTN) lstw[excl] = (uint16_t)(kb + b);
    ++excl;
  }
  asm volatile("s_waitcnt lgkmcnt(0)" ::: "memory");
  return total < LSTN ? total : LSTN;
}

__device__ __forceinline__ u32 lif_update(const float acc[4], float syn[4],
                                          float mem[4], u32 snib) {
  u32 nib = 0;
#pragma unroll
  for (int j = 0; j < 4; ++j) {
    float so = (float)((snib >> j) & 1u);
    float nmem = (DMc * mem[j] + SMc * syn[j]) * (1.0f - so);  // R1 shape
    float nsyn = DSc * syn[j] + acc[j];                         // R1 shape
    mem[j] = nmem;
    syn[j] = nsyn;
    if ((nmem - 1.0f) > 0.0f) nib |= (1u << j);
  }
  return nib;
}

// A+B interleaved dual gather: full batches of BOTH samples unguarded;
// guarded tail. Ascending k per sample, separate accumulators -> bit-exact.
__device__ __forceinline__ void gather_ab(const float* __restrict__ PKb,
                                          const uint16_t* __restrict__ lstA,
                                          int totA,
                                          const uint16_t* __restrict__ lstB,
                                          int totB, float aVA[4], float aWA[4],
                                          float aVB[4], float aWB[4]) {
  const int mn = totA < totB ? totA : totB;
  const int mx = totA > totB ? totA : totB;
  const int fullBoth = mn & ~7;

  int j0 = 0;
  for (; j0 < fullBoth; j0 += 8) {
    f32x4 va[8], wa[8], vb[8], wb[8];
#pragma unroll
    for (int u = 0; u < 8; ++u) {
      size_t offA = ((size_t)lstA[j0 + u]) << 9;
      va[u] = *(const f32x4*)(PKb + offA);
      wa[u] = *(const f32x4*)(PKb + offA + 256);
    }
#pragma unroll
    for (int u = 0; u < 8; ++u) {
      size_t offB = ((size_t)lstB[j0 + u]) << 9;
      vb[u] = *(const f32x4*)(PKb + offB);
      wb[u] = *(const f32x4*)(PKb + offB + 256);
    }
#pragma unroll
    for (int u = 0; u < 8; ++u) {
      aVA[0] += va[u].x; aVA[1] += va[u].y; aVA[2] += va[u].z; aVA[3] += va[u].w;
      aWA[0] += wa[u].x; aWA[1] += wa[u].y; aWA[2] += wa[u].z; aWA[3] += wa[u].w;
    }
#pragma unroll
    for (int u = 0; u < 8; ++u) {
      aVB[0] += vb[u].x; aVB[1] += vb[u].y; aVB[2] += vb[u].z; aVB[3] += vb[u].w;
      aWB[0] += wb[u].x; aWB[1] += wb[u].y; aWB[2] += wb[u].z; aWB[3] += wb[u].w;
    }
  }
  for (; j0 < mx; j0 += 8) {
    f32x4 va[8], wa[8], vb[8], wb[8];
#pragma unroll
    for (int u = 0; u < 8; ++u) {
      int ia = j0 + u;
      if (ia >= totA) ia = 0;
      size_t offA = ((size_t)lstA[ia]) << 9;
      va[u] = *(const f32x4*)(PKb + offA);
      wa[u] = *(const f32x4*)(PKb + offA + 256);
    }
#pragma unroll
    for (int u = 0; u < 8; ++u) {
      int ib = j0 + u;
      if (ib >= totB) ib = 0;
      size_t offB = ((size_t)lstB[ib]) << 9;
      vb[u] = *(const f32x4*)(PKb + offB);
      wb[u] = *(const f32x4*)(PKb + offB + 256);
    }
#pragma unroll
    for (int u = 0; u < 8; ++u)
      if (j0 + u < totA) {
        aVA[0] += va[u].x; aVA[1] += va[u].y; aVA[2] += va[u].z; aVA[3] += va[u].w;
        aWA[0] += wa[u].x; aWA[1] += wa[u].y; aWA[2] += wa[u].z; aWA[3] += wa[u].w;
      }
#pragma unroll
    for (int u = 0; u < 8; ++u)
      if (j0 + u < totB) {
        aVB[0] += vb[u].x; aVB[1] += vb[u].y; aVB[2] += vb[u].z; aVB[3] += vb[u].w;
        aWB[0] += wb[u].x; aWB[1] += wb[u].y; aWB[2] += wb[u].z; aWB[3] += wb[u].w;
      }
  }
}

template <int UXW>
__global__ __launch_bounds__(THREADS, 2) void rsnn_coop(
    const float* __restrict__ state, const float* __restrict__ target,
    const float* __restrict__ Wi, const float* __restrict__ bi,
    const float* __restrict__ Vr, const float* __restrict__ Wf,
    const float* __restrict__ bf, const float* __restrict__ Wo,
    const float* __restrict__ bo, float* __restrict__ out,
    char* __restrict__ wsb) {
  __shared__ float Wi_s[128 * COLS];      // 128 KB (fallback xw; pins 1 blk/CU)
  __shared__ uint16_t lstA_s[8][LSTN];    // 13 KB
  __shared__ uint16_t lstB_s[8][LSTN];    // 13 KB
  __shared__ int sh_xcd, sh_rank;

  u64* m1W = (u64*)(wsb + OFF_M1W);
  u64* m2H = (u64*)(wsb + OFF_M2H);
  u32* flags = (u32*)(wsb + OFF_FLAG);
  u32* cnt = (u32*)(wsb + OFF_CNT);
  u32* done = (u32*)(wsb + OFF_DONE);
  const float* PK = (const float*)(wsb + OFF_PK);
  const float* XW = (const float*)(wsb + OFF_XW);
  float* RO = (float*)(wsb + OFF_RO);   // aliases PK; used only post-loop

  const int tid = threadIdx.x;
  const int wv = tid >> 6;      // wave = 2 samples
  const int lane = tid & 63;    // lane = 4 columns

  if (tid == 0) {
    int x = __builtin_amdgcn_s_getreg(HWREG_XCC_ID) & 7;
    sh_xcd = x;
    sh_rank = atomicAdd(&cnt[x], 1u) & 31;
  }
  __syncthreads();
  const int xcd = sh_xcd;
  const int g = sh_rank;
  const int c0 = xcd * COLS;
  const int sA = g * SPB + wv * 2, sB = sA + 1;

  if constexpr (!UXW) {
    for (int i = tid; i < 128 * COLS; i += THREADS) {
      int k = i >> 8, c = i & 255;
      Wi_s[i] = Wi[(size_t)k * HD + c0 + c];
    }
  }
  uint16_t* lstA = &lstA_s[wv][0];
  uint16_t* lstB = &lstB_s[wv][0];
  if (lane == 0) { lstA[0] = 0; lstB[0] = 0; }   // guard rows for clamped loads

  float bir[4], bfr[4];
#pragma unroll
  for (int j = 0; j < 4; ++j) {
    bir[j] = bi[c0 + lane * 4 + j];
    bfr[j] = bf[c0 + lane * 4 + j];
  }

  float syn1A[4], mem1A[4], syn2A[4], mem2A[4];
  float syn1B[4], mem1B[4], syn2B[4], mem2B[4];
#pragma unroll
  for (int j = 0; j < 4; ++j) {
    syn1A[j] = 0.f; mem1A[j] = 0.f; syn2A[j] = 0.f; mem2A[j] = 0.f;
    syn1B[j] = 0.f; mem1B[j] = 0.f; syn2B[j] = 0.f; mem2B[j] = 0.f;
  }
  u32 nib1A = 0u, nib1B = 0u, nib2A = 0u, nib2B = 0u;
  float xwA[4], xwB[4];
  f32x4 xwNA, xwNB;

  const float* PKb = PK + (size_t)xcd * HD * 512 + lane * 4;
  const float* XWc = XW + c0 + lane * 4;
  u32* myflag = &flags[g * 32];

  __syncthreads();  // Wi_s / lst guards ready

  // xw(t) for A,B from Wi_s (k-ascending fmaf; fallback only)
  auto compute_xw = [&](int t2) {
#pragma unroll
    for (int j = 0; j < 4; ++j) { xwA[j] = bir[j]; xwB[j] = bir[j]; }
#pragma unroll
    for (int half = 0; half < 2; ++half) {
      const float* pA = (half ? target : state) + ((size_t)t2 * NB + sA) * 64;
      const float* pB = (half ? target : state) + ((size_t)t2 * NB + sB) * 64;
      for (int q = 0; q < 16; ++q) {
        f32x4 xa = *(const f32x4*)(pA + 4 * q);
        f32x4 xb = *(const f32x4*)(pB + 4 * q);
        float xav[4] = {xa.x, xa.y, xa.z, xa.w};
        float xbv[4] = {xb.x, xb.y, xb.z, xb.w};
#pragma unroll
        for (int kj = 0; kj < 4; ++kj) {
          const f32x4 w4 =
              *(const f32x4*)&Wi_s[(half * 64 + 4 * q + kj) * COLS + lane * 4];
          xwA[0] = fmaf(xav[kj], w4.x, xwA[0]);
          xwA[1] = fmaf(xav[kj], w4.y, xwA[1]);
          xwA[2] = fmaf(xav[kj], w4.z, xwA[2]);
          xwA[3] = fmaf(xav[kj], w4.w, xwA[3]);
          xwB[0] = fmaf(xbv[kj], w4.x, xwB[0]);
          xwB[1] = fmaf(xbv[kj], w4.y, xwB[1]);
          xwB[2] = fmaf(xbv[kj], w4.z, xwB[2]);
          xwB[3] = fmaf(xbv[kj], w4.w, xwB[3]);
        }
      }
    }
  };

  // ---- prologue: xw(0); LIF1(0); publish m1(0) into parity-0; rendezvous ----
  if constexpr (UXW) {
    f32x4 a = __builtin_nontemporal_load((const f32x4*)(XWc + (size_t)sA * HD));
    f32x4 b = __builtin_nontemporal_load((const f32x4*)(XWc + (size_t)sB * HD));
    xwA[0] = a.x; xwA[1] = a.y; xwA[2] = a.z; xwA[3] = a.w;
    xwB[0] = b.x; xwB[1] = b.y; xwB[2] = b.z; xwB[3] = b.w;
  } else {
    compute_xw(0);
  }
  nib1A = lif_update(xwA, syn1A, mem1A, 0u);
  nib1B = lif_update(xwB, syn1B, mem1B, 0u);
  {
    u64 E0 = __ballot(nib1A & 1u), E1 = __ballot(nib1A & 2u);
    u64 E2 = __ballot(nib1A & 4u), E3 = __ballot(nib1A & 8u);
    u64 F0 = __ballot(nib1B & 1u), F1 = __ballot(nib1B & 2u);
    u64 F2 = __ballot(nib1B & 4u), F3 = __ballot(nib1B & 8u);
    if (lane < 4)
      __hip_atomic_store(&m1W[(size_t)sA * NWPS + 4 * xcd + lane],
                         pack_word(E0, E1, E2, E3, lane), __ATOMIC_RELAXED,
                         __HIP_MEMORY_SCOPE_AGENT);
    else if (lane < 8)
      __hip_atomic_store(&m1W[(size_t)sB * NWPS + 4 * xcd + (lane - 4)],
                         pack_word(F0, F1, F2, F3, lane - 4), __ATOMIC_RELAXED,
                         __HIP_MEMORY_SCOPE_AGENT);
  }
  if constexpr (UXW) {
    xwNA = __builtin_nontemporal_load(
        (const f32x4*)(XWc + ((size_t)1 * NB + sA) * HD));
    xwNB = __builtin_nontemporal_load(
        (const f32x4*)(XWc + ((size_t)1 * NB + sB) * HD));
  }
  __syncthreads();
  if (tid == 0) {
    __hip_atomic_fetch_add(myflag, 1u, __ATOMIC_RELAXED, __HIP_MEMORY_SCOPE_AGENT);
    while (__hip_atomic_load(myflag, __ATOMIC_RELAXED,
                             __HIP_MEMORY_SCOPE_AGENT) < 8u)
      __builtin_amdgcn_s_sleep(2);
  }
  __syncthreads();

  // ---- main loop: step s gathers with m1(s); xw regs hold t=(s+1)>>1 ----
  for (int s = 0; s < NSTEPS; ++s) {
    if (s & 1) {
      if constexpr (UXW) {
        xwA[0] = xwNA.x; xwA[1] = xwNA.y; xwA[2] = xwNA.z; xwA[3] = xwNA.w;
        xwB[0] = xwNB.x; xwB[1] = xwNB.y; xwB[2] = xwNB.z; xwB[3] = xwNB.w;
      } else {
        if (s + 1 < NSTEPS) compute_xw((s + 1) >> 1);
      }
    }

    const u64* m1cur = m1W + (size_t)(s & 1) * NB * NWPS;
    u64* m1n = m1W + (size_t)((s + 1) & 1) * NB * NWPS;
    const bool last = (s == NSTEPS - 1);

    int totA, totB;
    build_ab(m1cur + (size_t)sA * NWPS, m1cur + (size_t)sB * NWPS, lstA, lstB,
             lane, totA, totB);

    float aVA[4] = {xwA[0], xwA[1], xwA[2], xwA[3]};
    float aWA[4] = {bfr[0], bfr[1], bfr[2], bfr[3]};
    float aVB[4] = {xwB[0], xwB[1], xwB[2], xwB[3]};
    float aWB[4] = {bfr[0], bfr[1], bfr[2], bfr[3]};
    gather_ab(PKb, lstA, totA, lstB, totB, aVA, aWA, aVB, aWB);

    // ---- CRITICAL PATH: LIF1(s+1) + publish m1(s+1) only ----
    if (!last) {
      nib1A = lif_update(aVA, syn1A, mem1A, nib1A);
      nib1B = lif_update(aVB, syn1B, mem1B, nib1B);
      u64 E0 = __ballot(nib1A & 1u), E1 = __ballot(nib1A & 2u);
      u64 E2 = __ballot(nib1A & 4u), E3 = __ballot(nib1A & 8u);
      u64 F0 = __ballot(nib1B & 1u), F1 = __ballot(nib1B & 2u);
      u64 F2 = __ballot(nib1B & 4u), F3 = __ballot(nib1B & 8u);
      if (lane < 4)
        __hip_atomic_store(&m1n[(size_t)sA * NWPS + 4 * xcd + lane],
                           pack_word(E0, E1, E2, E3, lane), __ATOMIC_RELAXED,
                           __HIP_MEMORY_SCOPE_AGENT);
      else if (lane < 8)
        __hip_atomic_store(&m1n[(size_t)sB * NWPS + 4 * xcd + (lane - 4)],
                           pack_word(F0, F1, F2, F3, lane - 4),
                           __ATOMIC_RELAXED, __HIP_MEMORY_SCOPE_AGENT);
    }
    __syncthreads();   // drain m1n stores (all waves)
    if (!last && tid == 0)
      __hip_atomic_fetch_add(myflag, 1u, __ATOMIC_RELAXED,
                             __HIP_MEMORY_SCOPE_AGENT);

    // ---- SHADOW (overlaps siblings' catch-up): LIF2(s) + m2H + xw pf ----
    nib2A = lif_update(aWA, syn2A, mem2A, nib2A);
    nib2B = lif_update(aWB, syn2B, mem2B, nib2B);
    {
      u64 D0 = __ballot(nib2A & 1u), D1 = __ballot(nib2A & 2u);
      u64 D2 = __ballot(nib2A & 4u), D3 = __ballot(nib2A & 8u);
      u64 G0 = __ballot(nib2B & 1u), G1 = __ballot(nib2B & 2u);
      u64 G2 = __ballot(nib2B & 4u), G3 = __ballot(nib2B & 8u);
      if (lane < 4)
        __hip_atomic_store(&m2H[((size_t)s * NB + sA) * NWPS + 4 * xcd + lane],
                           pack_word(D0, D1, D2, D3, lane), __ATOMIC_RELAXED,
                           __HIP_MEMORY_SCOPE_AGENT);
      else if (lane < 8)
        __hip_atomic_store(
            &m2H[((size_t)s * NB + sB) * NWPS + 4 * xcd + (lane - 4)],
            pack_word(G0, G1, G2, G3, lane - 4), __ATOMIC_RELAXED,
            __HIP_MEMORY_SCOPE_AGENT);
    }
    if ((s & 1) == 0) {
      if constexpr (UXW) {
        int t2 = (s >> 1) + 1;
        if (t2 < 64) {
          xwNA = __builtin_nontemporal_load(
              (const f32x4*)(XWc + ((size_t)t2 * NB + sA) * HD));
          xwNB = __builtin_nontemporal_load(
              (const f32x4*)(XWc + ((size_t)t2 * NB + sB) * HD));
        }
      }
    }

    // ---- wait for siblings ----
    if (!last) {
      __syncthreads();
      if (tid == 0) {
        u32 tgt = 8u * (u32)(s + 2);
        while (__hip_atomic_load(myflag, __ATOMIC_RELAXED,
                                 __HIP_MEMORY_SCOPE_AGENT) < tgt)
          __builtin_amdgcn_s_sleep(2);
      }
      __syncthreads();
    }
  }

  // ---- final rendezvous (full fence once: flush + replay-stale inv) ----
  __syncthreads();
  if (tid == 0) {
    __threadfence();
    __hip_atomic_fetch_add(done, 1u, __ATOMIC_RELEASE, __HIP_MEMORY_SCOPE_AGENT);
    while (__hip_atomic_load(done, __ATOMIC_RELAXED,
                             __HIP_MEMORY_SCOPE_AGENT) < (u32)NBLK)
      __builtin_amdgcn_s_sleep(8);
    __threadfence();
  }
  __syncthreads();

  // ==== PARALLEL READOUT ====
  // phase 1: all 8 waves compute Ir for this block's 2 samples x 128 steps.
  {
    const float bor = bo[lane];
    float* ROb = RO + (size_t)blockIdx.x * 2 * NSTEPS * 64;
    for (int i = 0; i < 32; ++i) {
      int j = wv + 8 * i;
      int loc = j >> 7, s = j & 127;
      int smp = blockIdx.x * 2 + loc;
      int total = build_list_ro(m2H + ((size_t)s * NB + smp) * NWPS, lstA, lane);
      float a = bor;
      for (int j0 = 0; j0 < total; j0 += 8) {
        float vv[8];
#pragma unroll
        for (int u = 0; u < 8; ++u) {
          int idx = j0 + u;
          if (idx >= total) idx = j0;
          vv[u] = Wo[(((size_t)lstA[idx]) << 6) + lane];
        }
#pragma unroll
        for (int u = 0; u < 8; ++u)
          if (j0 + u < total) a += vv[u];
      }
      ROb[(size_t)(loc * NSTEPS + s) * 64 + lane] = a;
    }
  }
  __syncthreads();   // Ir complete (block-local)

  // phase 2: 2 waves run the cheap leaky-integrator scan (identical math).
  if (wv < 2) {
    const int rsmp = blockIdx.x * 2 + wv;
    const float* ROb = RO + ((size_t)blockIdx.x * 2 + wv) * NSTEPS * 64;
    float synr = 0.f, memr = 0.f, roprev = 0.f;
    for (int s = 0; s < NSTEPS; ++s) {
      float a = ROb[(size_t)s * 64 + lane];
      float nmemr = DMc * memr + SMc * synr;  // R1 shape
      float nsynr = DSc * synr + a;           // R1 shape
      memr = nmemr;
      synr = nsynr;
      if (s & 1) {
        float v = 0.5f * (roprev + nmemr);
        size_t base = ((size_t)(s >> 1) * NB + rsmp) * 32;
        if (lane < 32) out[base + lane] = v;
        else out[(size_t)64 * NB * 32 + base + (lane - 32)] = v;
      } else {
        roprev = nmemr;
      }
    }
  }
}

extern "C" void kernel_launch(void* const* d_in, const int* in_sizes, int n_in,
                              void* d_out, int out_size, void* d_ws, size_t ws_size,
                              hipStream_t stream) {
  const float* state  = (const float*)d_in[0];
  const float* target = (const float*)d_in[1];
  const float* Wi     = (const float*)d_in[2];
  const float* bi     = (const float*)d_in[3];
  const float* Vr     = (const float*)d_in[4];
  const float* Wf     = (const float*)d_in[5];
  const float* bf     = (const float*)d_in[6];
  const float* Wo     = (const float*)d_in[7];
  const float* bo     = (const float*)d_in[8];
  float* out = (float*)d_out;
  char* wsb = (char*)d_ws;

  const int use_xw = (ws_size >= OFF_XW + SZ_XW) ? 1 : 0;

  init_ws<<<128, 256, 0, stream>>>((u64*)(wsb + OFF_M1W), (u32*)(wsb + OFF_FLAG),
                                   (u32*)(wsb + OFF_CNT), (u32*)(wsb + OFF_DONE));
  pack_kernel<<<HD, 256, 0, stream>>>(Vr, Wf, (float*)(wsb + OFF_PK));
  if (use_xw)
    xw_kernel<<<dim3(8, 2048), 256, 0, stream>>>(state, target, Wi, bi,
                                                 (float*)(wsb + OFF_XW));

  void* args[] = {(void*)&state, (void*)&target, (void*)&Wi, (void*)&bi,
                  (void*)&Vr, (void*)&Wf, (void*)&bf, (void*)&Wo, (void*)&bo,
                  (void*)&out, (void*)&wsb};
  if (use_xw)
    (void)hipLaunchCooperativeKernel(rsnn_coop<1>, dim3(NBLK), dim3(THREADS),
                                     args, 0, stream);
  else
    (void)hipLaunchCooperativeKernel(rsnn_coop<0>, dim3(NBLK), dim3(THREADS),
                                     args, 0, stream);
}